// Round 4
// baseline (208.979 us; speedup 1.0000x reference)
//
#include <hip/hip_runtime.h>
#include <math.h>
#include <stdint.h>

// n=256 samples, d=64, fp32 in/out. J-path bf16 MFMA.
//   K[m][l] = (1-h^2)[m] W1[m][l];  sKT[l][m] = K[m][l] (bf16), row 64 = h
//   W2sB[i][j][m] = bf16(W2[(i,j)][m] + W2[(j,i)][m])  (symmetric in i,j)
//   slab-frag af[t] (rows of W2s_i) and sKT-frag bf[t] are BOTH valid as A or B:
//     C1 = mfma(A=af[tr], B=bf[tc]) -> Ji[j][l]       (j=row, l=col)
//     C2 = mfma(A=bf[tr], B=af[tc]) -> Ji[l][j]       at the SAME (lane,reg)!
//   => q[l] += v_i * v_j * C1^2 * C2 fully in-register; no LDS transpose,
//      no barriers in the i-loop.
// v2-v4 history: 512thr (2 waves/SIMD) spilled ~19 regs at the 128-VGPR cap;
//     launch_bounds / waves_per_eu could not raise the cap. All ~45-48us.
//     Decomposition: MFMA ~7us + VALU ~9us per SIMD, ~30us stall unhidden.
// v5: 1024 threads (16 waves = 4 waves/SIMD, the only residency lever at
//     grid=256=1 block/CU) + register diet to fit 128 honestly:
//     no afn prefetch (-32), per-tc fused c1/c2 (-28), svj from LDS (-12).
//     Serial phases widened to 16 lanes/row.

typedef short short8 __attribute__((ext_vector_type(8)));
typedef float f32x4 __attribute__((ext_vector_type(4)));

__device__ __forceinline__ unsigned short f2bf(float f) {
  unsigned int u = __builtin_bit_cast(unsigned int, f);
  u += 0x7fffu + ((u >> 16) & 1u);
  return (unsigned short)(u >> 16);
}

__device__ __forceinline__ short8 as_short8(uint4 u) {
  union { uint4 a; short8 b; } cv; cv.a = u; return cv.b;
}

__global__ __launch_bounds__(256) void prep_w2s_kernel(const float* __restrict__ W2,
                                                       unsigned short* __restrict__ W2sB) {
  int g = blockIdx.x * 256 + threadIdx.x;      // each thread: 8 consecutive m
  int i = g >> 9, j = (g >> 3) & 63, m8 = (g & 7) << 3;
  const float* pa = &W2[((((i << 6) + j) << 6) + m8)];
  const float* pb = &W2[((((j << 6) + i) << 6) + m8)];
  float4 a0 = *(const float4*)pa, a1 = *(const float4*)(pa + 4);
  float4 b0 = *(const float4*)pb, b1 = *(const float4*)(pb + 4);
  short8 r;
  r[0] = (short)f2bf(a0.x + b0.x); r[1] = (short)f2bf(a0.y + b0.y);
  r[2] = (short)f2bf(a0.z + b0.z); r[3] = (short)f2bf(a0.w + b0.w);
  r[4] = (short)f2bf(a1.x + b1.x); r[5] = (short)f2bf(a1.y + b1.y);
  r[6] = (short)f2bf(a1.z + b1.z); r[7] = (short)f2bf(a1.w + b1.w);
  *(short8*)&W2sB[(size_t)g << 3] = r;
}

__global__ __launch_bounds__(1024) void conn_kernel(
    const float* __restrict__ x, const float* __restrict__ v,
    const float* __restrict__ W1, const float* __restrict__ b1,
    const float* __restrict__ b2, const float* __restrict__ W3,
    const unsigned short* __restrict__ W2sB, float* __restrict__ out) {
  __shared__ __align__(16) unsigned short sKT[80 * 80];  // rows 0-63 = K^T, 64 = h, 65-79 = 0
  __shared__ __align__(16) float sg[64 * 68];            // g, stride 68 (f32x4-aligned stores)
  __shared__ float spq[16][64];
  __shared__ __align__(16) float sh[64], sv[64], sx[64], sq[64];
  __shared__ __align__(16) float sz2[2][64];

  const int n = blockIdx.x, t = threadIdx.x;
  const int wv = t >> 6, lane = t & 63, ln15 = lane & 15, quad = lane >> 4;
  const int o16 = t >> 4, s16 = t & 15;

  if (t < 64) sx[t] = x[(n << 6) + t];
  else if (t < 128) sv[t - 64] = v[(n << 6) + (t - 64)];
  for (int e = t; e < 1280; e += 1024) sKT[5120 + e] = 0;  // zero rows 64..79
  __syncthreads();

  // h[o] = tanh(b1[o] + sum_l sx[l] W1[o][l]); 16 lanes per output row
  {
    const float* w1r = &W1[(o16 << 6) + (s16 << 2)];
    float4 wa = *(const float4*)w1r;
    float4 xa = *(const float4*)&sx[s16 << 2];
    float acc = wa.x * xa.x + wa.y * xa.y + wa.z * xa.z + wa.w * xa.w;
    acc += __shfl_xor(acc, 1);
    acc += __shfl_xor(acc, 2);
    acc += __shfl_xor(acc, 4);
    acc += __shfl_xor(acc, 8);
    if (s16 == 0) sh[o16] = tanhf(acc + b1[o16]);
  }
  __syncthreads();

  for (int e = t; e < 4096; e += 1024) {
    int m = e & 63, l = e >> 6;
    float hm = sh[m];
    sKT[l * 80 + m] = f2bf((1.f - hm * hm) * W1[(m << 6) + l]);
  }
  if (t < 64) sKT[64 * 80 + t] = f2bf(sh[t]);
  __syncthreads();

  // sKT frags: tiles 0..3 dual-use (A for C2 row-tile / B for C1 col-tile), tile 4 = ext (h)
  short8 bf[5][2];
  #pragma unroll
  for (int tc = 0; tc < 5; ++tc)
    #pragma unroll
    for (int ks = 0; ks < 2; ++ks)
      bf[tc][ks] = *(const short8*)&sKT[(tc * 16 + ln15) * 80 + ks * 32 + quad * 8];

  float qacc[4] = {0.f, 0.f, 0.f, 0.f};

  // Wave wv owns i in [4*wv, 4*wv+4). Slab frags: dual-use A(C1)/B(C2).
  const int foff = (ln15 << 6) + quad * 8;
  const unsigned short* sbase = W2sB + ((size_t)(4 * wv) << 12);

  #pragma unroll 1
  for (int ii = 0; ii < 4; ++ii) {
    const unsigned short* sp = sbase + ((size_t)ii << 12);
    uint4 af[4][2];
    #pragma unroll
    for (int tc = 0; tc < 4; ++tc) {
      af[tc][0] = *(const uint4*)(sp + (tc << 10) + foff);
      af[tc][1] = *(const uint4*)(sp + (tc << 10) + foff + 32);
    }
    const int i = 4 * wv + ii;
    const float vi = sv[i];

    #pragma unroll
    for (int tr = 0; tr < 4; ++tr) {
      short8 a0 = as_short8(af[tr][0]), a1 = as_short8(af[tr][1]);
      f32x4 svj = *(const f32x4*)&sv[tr * 16 + quad * 4];
      {
        f32x4 z4 = {0.f, 0.f, 0.f, 0.f};
        f32x4 u  = __builtin_amdgcn_mfma_f32_16x16x32_bf16(a0, bf[4][0], z4, 0, 0, 0);
        f32x4 ce = __builtin_amdgcn_mfma_f32_16x16x32_bf16(a1, bf[4][1], u, 0, 0, 0);
        if (ln15 == 0)  // g[i][j], j = 16*tr + 4*quad + r
          *(f32x4*)&sg[i * 68 + tr * 16 + quad * 4] = ce;
      }
      #pragma unroll
      for (int tc = 0; tc < 4; ++tc) {
        f32x4 z4 = {0.f, 0.f, 0.f, 0.f};
        f32x4 u  = __builtin_amdgcn_mfma_f32_16x16x32_bf16(a0, bf[tc][0], z4, 0, 0, 0);
        f32x4 c1 = __builtin_amdgcn_mfma_f32_16x16x32_bf16(a1, bf[tc][1], u, 0, 0, 0);
        f32x4 w  = __builtin_amdgcn_mfma_f32_16x16x32_bf16(bf[tr][0], as_short8(af[tc][0]), z4, 0, 0, 0);
        f32x4 c2 = __builtin_amdgcn_mfma_f32_16x16x32_bf16(bf[tr][1], as_short8(af[tc][1]), w, 0, 0, 0);
        float s = 0.f;
        #pragma unroll
        for (int r = 0; r < 4; ++r) {
          float a = c1[r];
          s = fmaf(a * a * c2[r], svj[r], s);
        }
        qacc[tc] = fmaf(s, vi, qacc[tc]);
      }
    }
  }

  // reduce qacc over quads (rows j), publish per-wave partial q
  #pragma unroll
  for (int tc = 0; tc < 4; ++tc) {
    float s = qacc[tc];
    s += __shfl_xor(s, 16, 64);
    s += __shfl_xor(s, 32, 64);
    if (quad == 0) spq[wv][tc * 16 + ln15] = s;
  }
  __syncthreads();  // first block-wide sync since setup

  for (int e = t; e < 4096; e += 1024) {   // g += b2 + b2^T
    int r = e >> 6, c = e & 63;
    sg[r * 68 + c] += b2[(r << 6) + c] + b2[(c << 6) + r];
  }
  __syncthreads();

  if (t < 64) {
    float s = 0.f;
    #pragma unroll
    for (int w = 0; w < 16; ++w) s += spq[w][t];
    sq[t] = s;
    sz2[0][t] = s / sg[t * 68 + t];   // Jacobi init
  }
  __syncthreads();

  // Jacobi: z' = z + (q - g z)/diag; 16 lanes/row, double-buffered (1 barrier/iter)
  {
    const int row = o16;
    const float* grow = &sg[row * 68];
    const float dinv = 1.f / grow[row];
    const float qr = sq[row];
    int pb = 0;
    for (int it = 0; it < 20; ++it) {
      float p = 0.f;
      #pragma unroll
      for (int cc = 0; cc < 4; ++cc) {
        int c = (cc << 4) + s16;     // sz2 reads: same addr per 4 rows -> broadcast
        p += grow[c] * sz2[pb][c];
      }
      p += __shfl_xor(p, 1);
      p += __shfl_xor(p, 2);
      p += __shfl_xor(p, 4);
      p += __shfl_xor(p, 8);
      if (s16 == 0) sz2[pb ^ 1][row] = sz2[pb][row] + (qr - p) * dinv;
      __syncthreads();
      pb ^= 1;
    }
  }
  // 20 iters (even) -> final z in sz2[0]

  // out[o] = sum_c v[c] W3[o][c] + 0.5 * sum_c z[c] W3[o][64+c]; 16 lanes/row
  {
    const float* w3r = &W3[o16 << 7];
    float4 wva = *(const float4*)&w3r[s16 << 2];
    float4 wda = *(const float4*)&w3r[64 + (s16 << 2)];
    float4 va = *(const float4*)&sv[s16 << 2];
    float4 za = *(const float4*)&sz2[0][s16 << 2];
    float acc = wva.x * va.x + wva.y * va.y + wva.z * va.z + wva.w * va.w
              + 0.5f * (wda.x * za.x + wda.y * za.y + wda.z * za.z + wda.w * za.w);
    acc += __shfl_xor(acc, 1);
    acc += __shfl_xor(acc, 2);
    acc += __shfl_xor(acc, 4);
    acc += __shfl_xor(acc, 8);
    if (s16 == 0) out[(n << 6) + o16] = acc;
  }
}

extern "C" void kernel_launch(void* const* d_in, const int* in_sizes, int n_in,
                              void* d_out, int out_size, void* d_ws, size_t ws_size,
                              hipStream_t stream) {
  (void)in_sizes; (void)n_in; (void)out_size; (void)ws_size;
  const float* x  = (const float*)d_in[1];
  const float* v  = (const float*)d_in[2];
  const float* W1 = (const float*)d_in[3];
  const float* b1 = (const float*)d_in[4];
  const float* W2 = (const float*)d_in[5];
  const float* b2 = (const float*)d_in[6];
  const float* W3 = (const float*)d_in[7];
  unsigned short* W2sB = (unsigned short*)d_ws;  // 64*64*64 bf16 = 512 KB

  hipLaunchKernelGGL(prep_w2s_kernel, dim3(128), dim3(256), 0, stream, W2, W2sB);
  hipLaunchKernelGGL(conn_kernel, dim3(256), dim3(1024), 0, stream,
                     x, v, W1, b1, b2, W3, W2sB, (float*)d_out);
}

// Round 5
// 110.754 us; speedup vs baseline: 1.8869x; 1.8869x over previous
//
#include <hip/hip_runtime.h>
#include <math.h>
#include <stdint.h>

// n=256 samples, d=64, fp32 in/out. J-path bf16 MFMA.
//   K[m][l] = (1-h^2)[m] W1[m][l];  sKT[l][m] = K[m][l] (bf16), row 64 = h
//   W2sB[i][j][m] = bf16(W2[(i,j)][m] + W2[(j,i)][m])  (symmetric in i,j)
//   slab-frag af[t] and sKT-frag bf[t] are BOTH valid as A or B:
//     C1 = mfma(A=af[tr], B=bf[tc]) -> Ji[j][l];  C2 = mfma(A=bf[tr], B=af[tc])
//     -> Ji[l][j] at the SAME (lane,reg) => q in-register, no LDS transpose.
// v2-v5 history: any block >256 thr gets VGPR-capped (128/64) by the
//     allocator's occupancy heuristic and spills the ~168-reg live set
//     into the i-loop (up to 200MB scratch traffic). 256-thr is the only
//     spill-free shape (v1: VGPR=168, WRITE 64KB).
// v6: residency via GRID, not block size. Kernel A: 512 blocks x 256 thr
//     (2 blocks/CU = 2 waves/SIMD, spill-free), each does HALF a sample
//     (i in [32*half,32*half+32), 8 i's/wave), writes g-rows + partial q
//     to workspace. Kernel B: 256 blocks, b2-sym + 20 Jacobi iters + out.

typedef short short8 __attribute__((ext_vector_type(8)));
typedef float f32x4 __attribute__((ext_vector_type(4)));

__device__ __forceinline__ unsigned short f2bf(float f) {
  unsigned int u = __builtin_bit_cast(unsigned int, f);
  u += 0x7fffu + ((u >> 16) & 1u);
  return (unsigned short)(u >> 16);
}

__device__ __forceinline__ short8 as_short8(uint4 u) {
  union { uint4 a; short8 b; } cv; cv.a = u; return cv.b;
}

__global__ __launch_bounds__(256) void prep_w2s_kernel(const float* __restrict__ W2,
                                                       unsigned short* __restrict__ W2sB) {
  int g = blockIdx.x * 256 + threadIdx.x;      // each thread: 8 consecutive m
  int i = g >> 9, j = (g >> 3) & 63, m8 = (g & 7) << 3;
  const float* pa = &W2[((((i << 6) + j) << 6) + m8)];
  const float* pb = &W2[((((j << 6) + i) << 6) + m8)];
  float4 a0 = *(const float4*)pa, a1 = *(const float4*)(pa + 4);
  float4 b0 = *(const float4*)pb, b1 = *(const float4*)(pb + 4);
  short8 r;
  r[0] = (short)f2bf(a0.x + b0.x); r[1] = (short)f2bf(a0.y + b0.y);
  r[2] = (short)f2bf(a0.z + b0.z); r[3] = (short)f2bf(a0.w + b0.w);
  r[4] = (short)f2bf(a1.x + b1.x); r[5] = (short)f2bf(a1.y + b1.y);
  r[6] = (short)f2bf(a1.z + b1.z); r[7] = (short)f2bf(a1.w + b1.w);
  *(short8*)&W2sB[(size_t)g << 3] = r;
}

// Kernel A: bid = half*256 + n. Computes g rows [32h,32h+32) -> gws[n],
// partial q -> qws[bid]. The i-loop is v1's proven 168-VGPR body.
__global__ __launch_bounds__(256) void connA_kernel(
    const float* __restrict__ x, const float* __restrict__ v,
    const float* __restrict__ W1, const float* __restrict__ b1,
    const unsigned short* __restrict__ W2sB,
    float* __restrict__ gws, float* __restrict__ qws) {
  __shared__ __align__(16) unsigned short sKT[80 * 80];  // rows 0-63 = K^T, 64 = h, 65-79 = 0
  __shared__ float spq[4][64];
  __shared__ __align__(16) float sh[64], sv[64], sx[64];

  const int bid = blockIdx.x;
  const int n = bid & 255, half = bid >> 8;
  const int t = threadIdx.x;
  const int wv = t >> 6, lane = t & 63, ln15 = lane & 15, quad = lane >> 4;

  if (t < 64) { sx[t] = x[(n << 6) + t]; sv[t] = v[(n << 6) + t]; }
  for (int e = t; e < 1280; e += 256) sKT[5120 + e] = 0;  // zero rows 64..79
  __syncthreads();

  if (t < 64) {
    float acc = b1[t];
    #pragma unroll 8
    for (int l = 0; l < 64; ++l) acc += sx[l] * W1[(t << 6) + l];
    sh[t] = tanhf(acc);
  }
  __syncthreads();

  for (int e = t; e < 4096; e += 256) {
    int m = e & 63, l = e >> 6;
    float hm = sh[m];
    sKT[l * 80 + m] = f2bf((1.f - hm * hm) * W1[(m << 6) + l]);
  }
  if (t < 64) sKT[64 * 80 + t] = f2bf(sh[t]);
  __syncthreads();

  // sKT frags: tiles 0..3 dual-use (A for C2 row-tile / B for C1 col-tile), tile 4 = ext (h)
  short8 bf[5][2];
  #pragma unroll
  for (int tc = 0; tc < 5; ++tc)
    #pragma unroll
    for (int ks = 0; ks < 2; ++ks)
      bf[tc][ks] = *(const short8*)&sKT[(tc * 16 + ln15) * 80 + ks * 32 + quad * 8];

  f32x4 svj[4];
  #pragma unroll
  for (int tr = 0; tr < 4; ++tr) svj[tr] = *(const f32x4*)&sv[tr * 16 + quad * 4];

  float qacc[4] = {0.f, 0.f, 0.f, 0.f};

  // Wave wv owns i in [32*half + 8*wv, +8). Slab frags: dual-use A(C1)/B(C2).
  const int foff = (ln15 << 6) + quad * 8;
  const int ibase = 32 * half + 8 * wv;
  const unsigned short* sbase = W2sB + ((size_t)ibase << 12);

  uint4 af[4][2], afn[4][2];
  #pragma unroll
  for (int tc = 0; tc < 4; ++tc) {
    af[tc][0] = *(const uint4*)(sbase + (tc << 10) + foff);
    af[tc][1] = *(const uint4*)(sbase + (tc << 10) + foff + 32);
  }

  for (int ii = 0; ii < 8; ++ii) {
    const unsigned short* spn = W2sB + ((size_t)(ibase + ((ii + 1) & 7)) << 12);
    #pragma unroll
    for (int tc = 0; tc < 4; ++tc) {
      afn[tc][0] = *(const uint4*)(spn + (tc << 10) + foff);
      afn[tc][1] = *(const uint4*)(spn + (tc << 10) + foff + 32);
    }
    const int i = ibase + ii;
    const float vi = sv[i];

    #pragma unroll
    for (int tr = 0; tr < 4; ++tr) {
      short8 a0 = as_short8(af[tr][0]), a1 = as_short8(af[tr][1]);
      f32x4 c1[4], c2[4], ce;
      #pragma unroll
      for (int tc = 0; tc < 4; ++tc) {
        f32x4 z4 = {0.f, 0.f, 0.f, 0.f};
        f32x4 u = __builtin_amdgcn_mfma_f32_16x16x32_bf16(a0, bf[tc][0], z4, 0, 0, 0);
        c1[tc]  = __builtin_amdgcn_mfma_f32_16x16x32_bf16(a1, bf[tc][1], u, 0, 0, 0);
        f32x4 w = __builtin_amdgcn_mfma_f32_16x16x32_bf16(bf[tr][0], as_short8(af[tc][0]), z4, 0, 0, 0);
        c2[tc]  = __builtin_amdgcn_mfma_f32_16x16x32_bf16(bf[tr][1], as_short8(af[tc][1]), w, 0, 0, 0);
      }
      {
        f32x4 z4 = {0.f, 0.f, 0.f, 0.f};
        f32x4 u = __builtin_amdgcn_mfma_f32_16x16x32_bf16(a0, bf[4][0], z4, 0, 0, 0);
        ce      = __builtin_amdgcn_mfma_f32_16x16x32_bf16(a1, bf[4][1], u, 0, 0, 0);
      }
      if (ln15 == 0)  // g[i][j], j = 16*tr + 4*quad + r -> global gws (no b2 yet)
        *(f32x4*)&gws[((size_t)n << 12) + (i << 6) + tr * 16 + quad * 4] = ce;

      #pragma unroll
      for (int tc = 0; tc < 4; ++tc) {
        float s = 0.f;
        #pragma unroll
        for (int r = 0; r < 4; ++r) {
          float a = c1[tc][r];
          s = fmaf(a * a * c2[tc][r], svj[tr][r], s);
        }
        qacc[tc] = fmaf(s, vi, qacc[tc]);
      }
    }
    #pragma unroll
    for (int tc = 0; tc < 4; ++tc) { af[tc][0] = afn[tc][0]; af[tc][1] = afn[tc][1]; }
  }

  // reduce qacc over quads (rows j), publish per-wave partial q
  #pragma unroll
  for (int tc = 0; tc < 4; ++tc) {
    float s = qacc[tc];
    s += __shfl_xor(s, 16, 64);
    s += __shfl_xor(s, 32, 64);
    if (quad == 0) spq[wv][tc * 16 + ln15] = s;
  }
  __syncthreads();

  if (t < 64) qws[(bid << 6) + t] = spq[0][t] + spq[1][t] + spq[2][t] + spq[3][t];
}

// Kernel B: per sample, g += b2 + b2^T, q = sum of halves, 20 Jacobi iters,
// out = v@W3[:, :64]^T + 0.5 z@W3[:, 64:]^T. 256 thr: 4 lanes per row.
__global__ __launch_bounds__(256) void connB_kernel(
    const float* __restrict__ v, const float* __restrict__ b2,
    const float* __restrict__ W3, const float* __restrict__ gws,
    const float* __restrict__ qws, float* __restrict__ out) {
  __shared__ __align__(16) float sg[64 * 68];
  __shared__ __align__(16) float sv[64], sq[64];
  __shared__ __align__(16) float sz2[2][64];

  const int n = blockIdx.x, t = threadIdx.x;
  const int row = t >> 2, s4 = t & 3;

  if (t < 64) {
    sv[t] = v[(n << 6) + t];
    sq[t] = qws[(n << 6) + t] + qws[(256 * 64) + (n << 6) + t];
  }
  for (int e = t; e < 4096; e += 256) {
    int r = e >> 6, c = e & 63;
    sg[r * 68 + c] = gws[((size_t)n << 12) + e] + b2[(r << 6) + c] + b2[(c << 6) + r];
  }
  __syncthreads();

  if (t < 64) sz2[0][t] = sq[t] / sg[t * 68 + t];
  __syncthreads();

  // Jacobi: z' = z + (q - g z)/diag; 4 lanes/row, double-buffered, 1 barrier/iter
  {
    const float* grow = &sg[row * 68];
    const float dinv = 1.f / grow[row];
    const float qr = sq[row];
    int pb = 0;
    for (int it = 0; it < 20; ++it) {
      float p = 0.f;
      #pragma unroll
      for (int cc = 0; cc < 16; ++cc) {
        int c = (cc << 2) + s4;   // bank = (4*row + 4*cc + s4) % 32 -> 2-way (free)
        p += grow[c] * sz2[pb][c];
      }
      p += __shfl_xor(p, 1);
      p += __shfl_xor(p, 2);
      if (s4 == 0) sz2[pb ^ 1][row] = sz2[pb][row] + (qr - p) * dinv;
      __syncthreads();
      pb ^= 1;
    }
  }
  // 20 iters (even) -> final z in sz2[0]

  {
    const float* w3r = &W3[row << 7];
    const int c0 = s4 << 4;
    float acc = 0.f;
    #pragma unroll
    for (int k = 0; k < 4; ++k) {
      float4 w4 = *(const float4*)&w3r[c0 + (k << 2)];
      float4 v4 = *(const float4*)&sv[c0 + (k << 2)];
      float4 d4 = *(const float4*)&w3r[64 + c0 + (k << 2)];
      float4 z4 = *(const float4*)&sz2[0][c0 + (k << 2)];
      acc += w4.x * v4.x + w4.y * v4.y + w4.z * v4.z + w4.w * v4.w
           + 0.5f * (d4.x * z4.x + d4.y * z4.y + d4.z * z4.z + d4.w * z4.w);
    }
    acc += __shfl_xor(acc, 1);
    acc += __shfl_xor(acc, 2);
    if (s4 == 0) out[(n << 6) + row] = acc;
  }
}

extern "C" void kernel_launch(void* const* d_in, const int* in_sizes, int n_in,
                              void* d_out, int out_size, void* d_ws, size_t ws_size,
                              hipStream_t stream) {
  (void)in_sizes; (void)n_in; (void)out_size; (void)ws_size;
  const float* x  = (const float*)d_in[1];
  const float* v  = (const float*)d_in[2];
  const float* W1 = (const float*)d_in[3];
  const float* b1 = (const float*)d_in[4];
  const float* W2 = (const float*)d_in[5];
  const float* b2 = (const float*)d_in[6];
  const float* W3 = (const float*)d_in[7];
  unsigned short* W2sB = (unsigned short*)d_ws;            // 512 KB bf16
  float* gws = (float*)((char*)d_ws + (512 << 10));        // 256*64*64 f32 = 4 MB
  float* qws = gws + 256 * 4096;                           // 512*64 f32 = 128 KB

  hipLaunchKernelGGL(prep_w2s_kernel, dim3(128), dim3(256), 0, stream, W2, W2sB);
  hipLaunchKernelGGL(connA_kernel, dim3(512), dim3(256), 0, stream,
                     x, v, W1, b1, W2sB, gws, qws);
  hipLaunchKernelGGL(connB_kernel, dim3(256), dim3(256), 0, stream,
                     v, b2, W3, gws, qws, (float*)d_out);
}

// Round 6
// 101.255 us; speedup vs baseline: 2.0639x; 1.0938x over previous
//
#include <hip/hip_runtime.h>
#include <math.h>
#include <stdint.h>

// n=256 samples, d=64, fp32 in/out. J-path bf16 MFMA.
//   K[m][l] = (1-h^2)[m] W1[m][l];  sKT[l][m] = K[m][l] (bf16), row 64 = h
//   W2sB[i][j][m] = bf16(W2[(i,j)][m] + W2[(j,i)][m])  (symmetric in i,j)
//   slab-frag af[t] and sKT-frag bf[t] are BOTH valid as A or B:
//     C1 = mfma(A=af[tr], B=bf[tc]) -> Ji[j][l];  C2 = mfma(A=bf[tr], B=af[tc])
//     -> Ji[l][j] at the SAME (lane,reg) => q in-register, no LDS transpose.
// v2-v6 ledger: >256-thr blocks get VGPR-capped (128@512thr, 64@1024thr);
//     the ~168-reg v1 body spills there. A/B grid-split (v6) was neutral
//     (gws roundtrip + extra launch ate the gain). Harness re-poisons the
//     256MB workspace every iter (~40us fill) - fixed cost, ignore.
// v7: single kernel, 512 thr (2 waves/SIMD resident - proven v3), with an
//     HONEST <=128-reg live set so residency comes spill-free:
//     no afn prefetch (-32), per-tc fused c1/c2 (-28), svj reloaded per tr
//     (-12), g-ext (h) fragment reloaded from LDS per use (-8).
//     Est live ~115-120 < 128 cap. WRITE_SIZE is the pass/fail signal.

typedef short short8 __attribute__((ext_vector_type(8)));
typedef float f32x4 __attribute__((ext_vector_type(4)));

__device__ __forceinline__ unsigned short f2bf(float f) {
  unsigned int u = __builtin_bit_cast(unsigned int, f);
  u += 0x7fffu + ((u >> 16) & 1u);
  return (unsigned short)(u >> 16);
}

__device__ __forceinline__ short8 as_short8(uint4 u) {
  union { uint4 a; short8 b; } cv; cv.a = u; return cv.b;
}

__global__ __launch_bounds__(256) void prep_w2s_kernel(const float* __restrict__ W2,
                                                       unsigned short* __restrict__ W2sB) {
  int g = blockIdx.x * 256 + threadIdx.x;      // each thread: 8 consecutive m
  int i = g >> 9, j = (g >> 3) & 63, m8 = (g & 7) << 3;
  const float* pa = &W2[((((i << 6) + j) << 6) + m8)];
  const float* pb = &W2[((((j << 6) + i) << 6) + m8)];
  float4 a0 = *(const float4*)pa, a1 = *(const float4*)(pa + 4);
  float4 b0 = *(const float4*)pb, b1 = *(const float4*)(pb + 4);
  short8 r;
  r[0] = (short)f2bf(a0.x + b0.x); r[1] = (short)f2bf(a0.y + b0.y);
  r[2] = (short)f2bf(a0.z + b0.z); r[3] = (short)f2bf(a0.w + b0.w);
  r[4] = (short)f2bf(a1.x + b1.x); r[5] = (short)f2bf(a1.y + b1.y);
  r[6] = (short)f2bf(a1.z + b1.z); r[7] = (short)f2bf(a1.w + b1.w);
  *(short8*)&W2sB[(size_t)g << 3] = r;
}

__global__ __launch_bounds__(512) void conn_kernel(
    const float* __restrict__ x, const float* __restrict__ v,
    const float* __restrict__ W1, const float* __restrict__ b1,
    const float* __restrict__ b2, const float* __restrict__ W3,
    const unsigned short* __restrict__ W2sB, float* __restrict__ out) {
  __shared__ __align__(16) unsigned short sKT[80 * 80];  // rows 0-63 = K^T, 64 = h, 65-79 = 0
  __shared__ __align__(16) float sg[64 * 68];            // g, stride 68 (f32x4-aligned stores)
  __shared__ float spq[8][64];
  __shared__ __align__(16) float sh[64], sv[64], sx[64], sq[64];
  __shared__ __align__(16) float sz2[2][64];

  const int n = blockIdx.x, t = threadIdx.x;
  const int wv = t >> 6, lane = t & 63, ln15 = lane & 15, quad = lane >> 4;
  const int o8 = t >> 3, s8 = t & 7;

  if (t < 64) sx[t] = x[(n << 6) + t];
  else if (t < 128) sv[t - 64] = v[(n << 6) + (t - 64)];
  for (int e = t; e < 1280; e += 512) sKT[5120 + e] = 0;  // zero rows 64..79
  __syncthreads();

  // h[o] = tanh(b1[o] + sum_l sx[l] W1[o][l]); 8 lanes per output, shfl reduce
  {
    const float* w1r = &W1[(o8 << 6) + (s8 << 3)];
    float4 wa = *(const float4*)w1r, wb = *(const float4*)(w1r + 4);
    float4 xa = *(const float4*)&sx[s8 << 3], xb = *(const float4*)&sx[(s8 << 3) + 4];
    float acc = wa.x * xa.x + wa.y * xa.y + wa.z * xa.z + wa.w * xa.w
              + wb.x * xb.x + wb.y * xb.y + wb.z * xb.z + wb.w * xb.w;
    acc += __shfl_xor(acc, 1);
    acc += __shfl_xor(acc, 2);
    acc += __shfl_xor(acc, 4);
    if (s8 == 0) sh[o8] = tanhf(acc + b1[o8]);
  }
  __syncthreads();

  for (int e = t; e < 4096; e += 512) {
    int m = e & 63, l = e >> 6;
    float hm = sh[m];
    sKT[l * 80 + m] = f2bf((1.f - hm * hm) * W1[(m << 6) + l]);
  }
  if (t < 64) sKT[64 * 80 + t] = f2bf(sh[t]);
  __syncthreads();

  // sKT frags: tiles 0..3 dual-use (A for C2 row-tile / B for C1 col-tile).
  // Tile 4 (ext: h row) is reloaded from LDS per use to save 8 VGPRs.
  short8 bf[4][2];
  #pragma unroll
  for (int tc = 0; tc < 4; ++tc)
    #pragma unroll
    for (int ks = 0; ks < 2; ++ks)
      bf[tc][ks] = *(const short8*)&sKT[(tc * 16 + ln15) * 80 + ks * 32 + quad * 8];

  float qacc[4] = {0.f, 0.f, 0.f, 0.f};

  // Wave wv owns i in [8*wv, 8*wv+8). Slab frags: dual-use A(C1)/B(C2).
  const int foff = (ln15 << 6) + quad * 8;
  const int extoff = (64 + ln15) * 80 + quad * 8;   // h-row frag base (+ks*32)
  const unsigned short* sbase = W2sB + ((size_t)(8 * wv) << 12);

  #pragma unroll 1
  for (int ii = 0; ii < 8; ++ii) {
    const unsigned short* sp = sbase + ((size_t)ii << 12);
    uint4 af[4][2];
    #pragma unroll
    for (int tc = 0; tc < 4; ++tc) {
      af[tc][0] = *(const uint4*)(sp + (tc << 10) + foff);
      af[tc][1] = *(const uint4*)(sp + (tc << 10) + foff + 32);
    }
    const int i = 8 * wv + ii;
    const float vi = sv[i];

    #pragma unroll
    for (int tr = 0; tr < 4; ++tr) {
      short8 a0 = as_short8(af[tr][0]), a1 = as_short8(af[tr][1]);
      f32x4 svj = *(const f32x4*)&sv[tr * 16 + quad * 4];
      {
        short8 e0 = *(const short8*)&sKT[extoff];
        short8 e1 = *(const short8*)&sKT[extoff + 32];
        f32x4 z4 = {0.f, 0.f, 0.f, 0.f};
        f32x4 u  = __builtin_amdgcn_mfma_f32_16x16x32_bf16(a0, e0, z4, 0, 0, 0);
        f32x4 ce = __builtin_amdgcn_mfma_f32_16x16x32_bf16(a1, e1, u, 0, 0, 0);
        if (ln15 == 0)  // g[i][j], j = 16*tr + 4*quad + r
          *(f32x4*)&sg[i * 68 + tr * 16 + quad * 4] = ce;
      }
      #pragma unroll
      for (int tc = 0; tc < 4; ++tc) {
        f32x4 z4 = {0.f, 0.f, 0.f, 0.f};
        f32x4 u  = __builtin_amdgcn_mfma_f32_16x16x32_bf16(a0, bf[tc][0], z4, 0, 0, 0);
        f32x4 c1 = __builtin_amdgcn_mfma_f32_16x16x32_bf16(a1, bf[tc][1], u, 0, 0, 0);
        f32x4 w  = __builtin_amdgcn_mfma_f32_16x16x32_bf16(bf[tr][0], as_short8(af[tc][0]), z4, 0, 0, 0);
        f32x4 c2 = __builtin_amdgcn_mfma_f32_16x16x32_bf16(bf[tr][1], as_short8(af[tc][1]), w, 0, 0, 0);
        float s = 0.f;
        #pragma unroll
        for (int r = 0; r < 4; ++r) {
          float a = c1[r];
          s = fmaf(a * a * c2[r], svj[r], s);
        }
        qacc[tc] = fmaf(s, vi, qacc[tc]);
      }
    }
  }

  // reduce qacc over quads (rows j), publish per-wave partial q
  #pragma unroll
  for (int tc = 0; tc < 4; ++tc) {
    float s = qacc[tc];
    s += __shfl_xor(s, 16, 64);
    s += __shfl_xor(s, 32, 64);
    if (quad == 0) spq[wv][tc * 16 + ln15] = s;
  }
  __syncthreads();  // first block-wide sync since setup

  for (int e = t; e < 4096; e += 512) {   // g += b2 + b2^T
    int r = e >> 6, c = e & 63;
    sg[r * 68 + c] += b2[(r << 6) + c] + b2[(c << 6) + r];
  }
  __syncthreads();

  if (t < 64) {
    float s = spq[0][t] + spq[1][t] + spq[2][t] + spq[3][t]
            + spq[4][t] + spq[5][t] + spq[6][t] + spq[7][t];
    sq[t] = s;
    sz2[0][t] = s / sg[t * 68 + t];   // Jacobi init
  }
  __syncthreads();

  // Jacobi: z' = z + (q - g z)/diag; 8 lanes/row, double-buffered (1 barrier/iter)
  {
    const int row = o8;
    const float* grow = &sg[row * 68];
    const float dinv = 1.f / grow[row];
    const float qr = sq[row];
    int pb = 0;
    for (int it = 0; it < 20; ++it) {
      float p = 0.f;
      #pragma unroll
      for (int cc = 0; cc < 8; ++cc) {
        int c = (cc << 3) + s8;      // bank = (4*row + 8*cc + s8) % 32 -> 2-way (free)
        p += grow[c] * sz2[pb][c];
      }
      p += __shfl_xor(p, 1);
      p += __shfl_xor(p, 2);
      p += __shfl_xor(p, 4);
      if (s8 == 0) sz2[pb ^ 1][row] = sz2[pb][row] + (qr - p) * dinv;
      __syncthreads();
      pb ^= 1;
    }
  }
  // 20 iters (even) -> final z in sz2[0]

  // out[o] = sum_c v[c] W3[o][c] + 0.5 * sum_c z[c] W3[o][64+c]; 8 lanes/row
  {
    const float* w3r = &W3[o8 << 7];
    float4 wva = *(const float4*)&w3r[s8 << 3];
    float4 wvb = *(const float4*)&w3r[(s8 << 3) + 4];
    float4 wda = *(const float4*)&w3r[64 + (s8 << 3)];
    float4 wdb = *(const float4*)&w3r[64 + (s8 << 3) + 4];
    float4 va = *(const float4*)&sv[s8 << 3], vb = *(const float4*)&sv[(s8 << 3) + 4];
    float4 za = *(const float4*)&sz2[0][s8 << 3], zb = *(const float4*)&sz2[0][(s8 << 3) + 4];
    float acc = wva.x * va.x + wva.y * va.y + wva.z * va.z + wva.w * va.w
              + wvb.x * vb.x + wvb.y * vb.y + wvb.z * vb.z + wvb.w * vb.w
              + 0.5f * (wda.x * za.x + wda.y * za.y + wda.z * za.z + wda.w * za.w
                      + wdb.x * zb.x + wdb.y * zb.y + wdb.z * zb.z + wdb.w * zb.w);
    acc += __shfl_xor(acc, 1);
    acc += __shfl_xor(acc, 2);
    acc += __shfl_xor(acc, 4);
    if (s8 == 0) out[(n << 6) + o8] = acc;
  }
}

extern "C" void kernel_launch(void* const* d_in, const int* in_sizes, int n_in,
                              void* d_out, int out_size, void* d_ws, size_t ws_size,
                              hipStream_t stream) {
  (void)in_sizes; (void)n_in; (void)out_size; (void)ws_size;
  const float* x  = (const float*)d_in[1];
  const float* v  = (const float*)d_in[2];
  const float* W1 = (const float*)d_in[3];
  const float* b1 = (const float*)d_in[4];
  const float* W2 = (const float*)d_in[5];
  const float* b2 = (const float*)d_in[6];
  const float* W3 = (const float*)d_in[7];
  unsigned short* W2sB = (unsigned short*)d_ws;  // 64*64*64 bf16 = 512 KB

  hipLaunchKernelGGL(prep_w2s_kernel, dim3(128), dim3(256), 0, stream, W2, W2sB);
  hipLaunchKernelGGL(conn_kernel, dim3(256), dim3(512), 0, stream,
                     x, v, W1, b1, b2, W3, W2sB, (float*)d_out);
}

// Round 7
// 101.190 us; speedup vs baseline: 2.0652x; 1.0006x over previous
//
#include <hip/hip_runtime.h>
#include <math.h>
#include <stdint.h>

// n=256 samples, d=64, fp32 in/out. J-path bf16 MFMA.
//   K[m][l] = (1-h^2)[m] W1[m][l];  sKT[l][m] = K[m][l] (bf16), row 64 = h
//   W2sB[i][j][m] = bf16(W2[(i,j)][m] + W2[(j,i)][m])  (symmetric in i,j)
//   slab-frag af[t] and sKT-frag bf[t] are BOTH valid as A or B:
//     C1 = mfma(A=af[tr], B=bf[tc]) -> Ji[j][l];  C2 = mfma(A=bf[tr], B=af[tc])
//     -> Ji[l][j] at the SAME (lane,reg) => q in-register, no LDS transpose.
// Ledger: >256-thr blocks are VGPR-capped by the allocator (128@512thr,
//   64@1024thr); v7's diet body fits 128 spill-free at 512thr (2 w/SIMD)
//   -> conn dropped 45.5 -> <40us (fell out of rocprof top-5; fills ~40us
//   are harness-fixed). Remaining stall: slab loads from L2 consumed
//   immediately (no prefetch - no VGPR headroom for one).
// v8: VGPR-free prefetch via global_load_lds: per-wave 2x8KB LDS slab
//   double-buffer (128KB; total LDS 158.3KB, 1 block/CU which grid=256
//   forces anyway). DMA of slab ii+1 issues at top of iter ii and flies
//   across the whole compute phase; only a per-wave vmcnt(0) at iter top,
//   still no barriers in the i-loop. Linear DMA + 16B-slot XOR swizzle
//   (slot ^= row&7) on BOTH global source and ds_read addresses keeps
//   frag reads ~2-way bank-conflict (linear would be 16-way).
//   Post-i-loop scratch (spq/sq/sz) overlays dead sKT rows 0-63.

typedef short short8 __attribute__((ext_vector_type(8)));
typedef float f32x4 __attribute__((ext_vector_type(4)));

__device__ __forceinline__ unsigned short f2bf(float f) {
  unsigned int u = __builtin_bit_cast(unsigned int, f);
  u += 0x7fffu + ((u >> 16) & 1u);
  return (unsigned short)(u >> 16);
}

__device__ __forceinline__ short8 as_short8(uint4 u) {
  union { uint4 a; short8 b; } cv; cv.a = u; return cv.b;
}

// DMA one 8KB slab (64 rows x 128B) global->LDS, 16B/lane/instr, 8 instrs.
// Source pre-swizzled so lds[row j][16B-slot s] = global(j, s ^ (j&7)).
__device__ __forceinline__ void stage_slab(const unsigned short* gslab,
                                           unsigned short* lbase, int lane) {
  const int srcoff = ((lane >> 3) << 6) + (((lane & 7) ^ (lane >> 3)) << 3);  // shorts
  const unsigned short* gsrc = gslab + srcoff;
  #pragma unroll
  for (int k = 0; k < 8; ++k) {
    __builtin_amdgcn_global_load_lds(
        (const __attribute__((address_space(1))) unsigned int*)(gsrc + (k << 9)),
        (__attribute__((address_space(3))) unsigned int*)(lbase + (k << 9)),
        16, 0, 0);
  }
}

__global__ __launch_bounds__(256) void prep_w2s_kernel(const float* __restrict__ W2,
                                                       unsigned short* __restrict__ W2sB) {
  int g = blockIdx.x * 256 + threadIdx.x;      // each thread: 8 consecutive m
  int i = g >> 9, j = (g >> 3) & 63, m8 = (g & 7) << 3;
  const float* pa = &W2[((((i << 6) + j) << 6) + m8)];
  const float* pb = &W2[((((j << 6) + i) << 6) + m8)];
  float4 a0 = *(const float4*)pa, a1 = *(const float4*)(pa + 4);
  float4 b0 = *(const float4*)pb, b1 = *(const float4*)(pb + 4);
  short8 r;
  r[0] = (short)f2bf(a0.x + b0.x); r[1] = (short)f2bf(a0.y + b0.y);
  r[2] = (short)f2bf(a0.z + b0.z); r[3] = (short)f2bf(a0.w + b0.w);
  r[4] = (short)f2bf(a1.x + b1.x); r[5] = (short)f2bf(a1.y + b1.y);
  r[6] = (short)f2bf(a1.z + b1.z); r[7] = (short)f2bf(a1.w + b1.w);
  *(short8*)&W2sB[(size_t)g << 3] = r;
}

__global__ __launch_bounds__(512) void conn_kernel(
    const float* __restrict__ x, const float* __restrict__ v,
    const float* __restrict__ W1, const float* __restrict__ b1,
    const float* __restrict__ b2, const float* __restrict__ W3,
    const unsigned short* __restrict__ W2sB, float* __restrict__ out) {
  __shared__ __align__(16) unsigned short sAF[8][2][4096];  // per-wave slab dbuf, 128KB
  __shared__ __align__(16) unsigned short sKT[80 * 80];  // rows 0-63 = K^T, 64 = h, 65-79 = 0
  __shared__ __align__(16) float sg[64 * 68];            // g, stride 68 (f32x4-aligned stores)
  __shared__ __align__(16) float sh[64], sv[64], sx[64];

  // Overlays into sKT rows 0-63 (bytes 0..10239): dead once bf frags are
  // pinned; ext reads use only rows 64-79 (bytes >= 10240).
  float* const spq = (float*)sKT;          // [8][64] = 2048B
  float* const sq  = (float*)sKT + 512;    // 256B
  float* const szz = (float*)sKT + 576;    // [2][64] = 512B

  const int n = blockIdx.x, t = threadIdx.x;
  const int wv = t >> 6, lane = t & 63, ln15 = lane & 15, quad = lane >> 4;
  const int o8 = t >> 3, s8 = t & 7;

  if (t < 64) sx[t] = x[(n << 6) + t];
  else if (t < 128) sv[t - 64] = v[(n << 6) + (t - 64)];
  for (int e = t; e < 1280; e += 512) sKT[5120 + e] = 0;  // zero rows 64..79
  __syncthreads();

  // h[o] = tanh(b1[o] + sum_l sx[l] W1[o][l]); 8 lanes per output, shfl reduce
  {
    const float* w1r = &W1[(o8 << 6) + (s8 << 3)];
    float4 wa = *(const float4*)w1r, wb = *(const float4*)(w1r + 4);
    float4 xa = *(const float4*)&sx[s8 << 3], xb = *(const float4*)&sx[(s8 << 3) + 4];
    float acc = wa.x * xa.x + wa.y * xa.y + wa.z * xa.z + wa.w * xa.w
              + wb.x * xb.x + wb.y * xb.y + wb.z * xb.z + wb.w * xb.w;
    acc += __shfl_xor(acc, 1);
    acc += __shfl_xor(acc, 2);
    acc += __shfl_xor(acc, 4);
    if (s8 == 0) sh[o8] = tanhf(acc + b1[o8]);
  }
  __syncthreads();

  for (int e = t; e < 4096; e += 512) {
    int m = e & 63, l = e >> 6;
    float hm = sh[m];
    sKT[l * 80 + m] = f2bf((1.f - hm * hm) * W1[(m << 6) + l]);
  }
  if (t < 64) sKT[64 * 80 + t] = f2bf(sh[t]);
  __syncthreads();

  // sKT frags: tiles 0..3 dual-use (A for C2 row-tile / B for C1 col-tile).
  // Tile 4 (ext: h row) is reloaded from LDS per use (VGPR diet).
  short8 bf[4][2];
  #pragma unroll
  for (int tc = 0; tc < 4; ++tc)
    #pragma unroll
    for (int ks = 0; ks < 2; ++ks)
      bf[tc][ks] = *(const short8*)&sKT[(tc * 16 + ln15) * 80 + ks * 32 + quad * 8];

  float qacc[4] = {0.f, 0.f, 0.f, 0.f};

  // Wave wv owns i in [8*wv, 8*wv+8). Slab frags from LDS, swizzled reads:
  // element slot' = slot ^ (ln15&7); af[tc][1] address = [0] address ^ 32.
  const int f0 = (ln15 << 6) + (((quad ^ ln15) & 7) << 3);
  const int extoff = (64 + ln15) * 80 + quad * 8;   // h-row frag base (+32 for ks=1)
  unsigned short* const myAF = &sAF[wv][0][0];
  const unsigned short* const gbase = W2sB + ((size_t)(8 * wv) << 12);

  stage_slab(gbase, myAF, lane);   // prologue: slab 0 -> buf 0

  #pragma unroll 1
  for (int ii = 0; ii < 8; ++ii) {
    asm volatile("s_waitcnt vmcnt(0)" ::: "memory");   // buf[ii&1] DMA complete
    __builtin_amdgcn_sched_barrier(0);
    if (ii < 7)  // prefetch next slab into the other buffer; flies across compute
      stage_slab(gbase + ((size_t)(ii + 1) << 12), myAF + (((ii & 1) ^ 1) << 12), lane);

    const unsigned short* buf = myAF + ((ii & 1) << 12);
    uint4 af[4][2];
    #pragma unroll
    for (int tc = 0; tc < 4; ++tc) {
      af[tc][0] = *(const uint4*)&buf[(tc << 10) + f0];
      af[tc][1] = *(const uint4*)&buf[(tc << 10) + (f0 ^ 32)];
    }
    const int i = 8 * wv + ii;
    const float vi = sv[i];

    #pragma unroll
    for (int tr = 0; tr < 4; ++tr) {
      short8 a0 = as_short8(af[tr][0]), a1 = as_short8(af[tr][1]);
      f32x4 svj = *(const f32x4*)&sv[tr * 16 + quad * 4];
      {
        short8 e0 = *(const short8*)&sKT[extoff];
        short8 e1 = *(const short8*)&sKT[extoff + 32];
        f32x4 z4 = {0.f, 0.f, 0.f, 0.f};
        f32x4 u  = __builtin_amdgcn_mfma_f32_16x16x32_bf16(a0, e0, z4, 0, 0, 0);
        f32x4 ce = __builtin_amdgcn_mfma_f32_16x16x32_bf16(a1, e1, u, 0, 0, 0);
        if (ln15 == 0)  // g[i][j], j = 16*tr + 4*quad + r
          *(f32x4*)&sg[i * 68 + tr * 16 + quad * 4] = ce;
      }
      #pragma unroll
      for (int tc = 0; tc < 4; ++tc) {
        f32x4 z4 = {0.f, 0.f, 0.f, 0.f};
        f32x4 u  = __builtin_amdgcn_mfma_f32_16x16x32_bf16(a0, bf[tc][0], z4, 0, 0, 0);
        f32x4 c1 = __builtin_amdgcn_mfma_f32_16x16x32_bf16(a1, bf[tc][1], u, 0, 0, 0);
        f32x4 w  = __builtin_amdgcn_mfma_f32_16x16x32_bf16(bf[tr][0], as_short8(af[tc][0]), z4, 0, 0, 0);
        f32x4 c2 = __builtin_amdgcn_mfma_f32_16x16x32_bf16(bf[tr][1], as_short8(af[tc][1]), w, 0, 0, 0);
        float s = 0.f;
        #pragma unroll
        for (int r = 0; r < 4; ++r) {
          float a = c1[r];
          s = fmaf(a * a * c2[r], svj[r], s);
        }
        qacc[tc] = fmaf(s, vi, qacc[tc]);
      }
    }
  }

  // reduce qacc over quads (rows j), publish per-wave partial q.
  // spq overlays sKT rows 0-63: dead for ALL waves during/after the i-loop
  // (only rows 64-79 are read as ext frags), so no barrier needed first.
  #pragma unroll
  for (int tc = 0; tc < 4; ++tc) {
    float s = qacc[tc];
    s += __shfl_xor(s, 16, 64);
    s += __shfl_xor(s, 32, 64);
    if (quad == 0) spq[(wv << 6) + tc * 16 + ln15] = s;
  }
  __syncthreads();  // first block-wide sync since setup

  for (int e = t; e < 4096; e += 512) {   // g += b2 + b2^T
    int r = e >> 6, c = e & 63;
    sg[r * 68 + c] += b2[(r << 6) + c] + b2[(c << 6) + r];
  }
  __syncthreads();

  if (t < 64) {
    float s = spq[t] + spq[64 + t] + spq[128 + t] + spq[192 + t]
            + spq[256 + t] + spq[320 + t] + spq[384 + t] + spq[448 + t];
    sq[t] = s;
    szz[t] = s / sg[t * 68 + t];   // Jacobi init (buffer 0)
  }
  __syncthreads();

  // Jacobi: z' = z + (q - g z)/diag; 8 lanes/row, double-buffered (1 barrier/iter)
  {
    const int row = o8;
    const float* grow = &sg[row * 68];
    const float dinv = 1.f / grow[row];
    const float qr = sq[row];
    int pb = 0;
    for (int it = 0; it < 20; ++it) {
      float p = 0.f;
      #pragma unroll
      for (int cc = 0; cc < 8; ++cc) {
        int c = (cc << 3) + s8;      // bank = (4*row + 8*cc + s8) % 32 -> 2-way (free)
        p += grow[c] * szz[(pb << 6) + c];
      }
      p += __shfl_xor(p, 1);
      p += __shfl_xor(p, 2);
      p += __shfl_xor(p, 4);
      if (s8 == 0) szz[((pb ^ 1) << 6) + row] = szz[(pb << 6) + row] + (qr - p) * dinv;
      __syncthreads();
      pb ^= 1;
    }
  }
  // 20 iters (even) -> final z in szz[0..63]

  // out[o] = sum_c v[c] W3[o][c] + 0.5 * sum_c z[c] W3[o][64+c]; 8 lanes/row
  {
    const float* w3r = &W3[o8 << 7];
    float4 wva = *(const float4*)&w3r[s8 << 3];
    float4 wvb = *(const float4*)&w3r[(s8 << 3) + 4];
    float4 wda = *(const float4*)&w3r[64 + (s8 << 3)];
    float4 wdb = *(const float4*)&w3r[64 + (s8 << 3) + 4];
    float4 va = *(const float4*)&sv[s8 << 3], vb = *(const float4*)&sv[(s8 << 3) + 4];
    float4 za = *(const float4*)&szz[s8 << 3], zb = *(const float4*)&szz[(s8 << 3) + 4];
    float acc = wva.x * va.x + wva.y * va.y + wva.z * va.z + wva.w * va.w
              + wvb.x * vb.x + wvb.y * vb.y + wvb.z * vb.z + wvb.w * vb.w
              + 0.5f * (wda.x * za.x + wda.y * za.y + wda.z * za.z + wda.w * za.w
                      + wdb.x * zb.x + wdb.y * zb.y + wdb.z * zb.z + wdb.w * zb.w);
    acc += __shfl_xor(acc, 1);
    acc += __shfl_xor(acc, 2);
    acc += __shfl_xor(acc, 4);
    if (s8 == 0) out[(n << 6) + o8] = acc;
  }
}

extern "C" void kernel_launch(void* const* d_in, const int* in_sizes, int n_in,
                              void* d_out, int out_size, void* d_ws, size_t ws_size,
                              hipStream_t stream) {
  (void)in_sizes; (void)n_in; (void)out_size; (void)ws_size;
  const float* x  = (const float*)d_in[1];
  const float* v  = (const float*)d_in[2];
  const float* W1 = (const float*)d_in[3];
  const float* b1 = (const float*)d_in[4];
  const float* W2 = (const float*)d_in[5];
  const float* b2 = (const float*)d_in[6];
  const float* W3 = (const float*)d_in[7];
  unsigned short* W2sB = (unsigned short*)d_ws;  // 64*64*64 bf16 = 512 KB

  hipLaunchKernelGGL(prep_w2s_kernel, dim3(128), dim3(256), 0, stream, W2, W2sB);
  hipLaunchKernelGGL(conn_kernel, dim3(256), dim3(512), 0, stream,
                     x, v, W1, b1, b2, W3, W2sB, (float*)d_out);
}

// Round 8
// 98.368 us; speedup vs baseline: 2.1245x; 1.0287x over previous
//
#include <hip/hip_runtime.h>
#include <math.h>
#include <stdint.h>

// n=256 samples, d=64, fp32 in/out. J-path bf16 MFMA.
//   K[m][l] = (1-h^2)[m] W1[m][l];  sKT[l][m] = K[m][l] (bf16), row 64 = h
//   W2sB[i][j][m] = bf16(W2[(i,j)][m] + W2[(j,i)][m])  (symmetric in i,j)
//   slab-frag af[t] and sKT-frag bf[t] are BOTH valid as A or B:
//     C1 = mfma(A=af[tr], B=bf[tc]) -> Ji[j][l];  C2 = mfma(A=bf[tr], B=af[tc])
//     -> Ji[l][j] at the SAME (lane,reg) => q in-register, no LDS transpose.
// Ledger: >256-thr blocks are VGPR-capped by the allocator (128@512thr);
//   v7 diet fits 128 spill-free at 512thr (2 w/SIMD): conn 45.5 -> <39.
//   v8 DMA slab double-buffer: NEUTRAL -> i-loop is not load-bound (L2-warm
//   + 2 waves already cover it). Harness fill (~40us) + reset dispatches
//   (~20us) are fixed costs.
// v9: restore v1's c1[4]/c2[4] MFMA batching (8 independent 2-deep chains
//   in flight before any VALU consume) which v7's diet over-removed; the
//   per-tc fused form exposed ~4x MFMA latency per tc-step. Fits 128 now
//   because v8's DMA staging freed the 32 afn regs: live ~122-126.

typedef short short8 __attribute__((ext_vector_type(8)));
typedef float f32x4 __attribute__((ext_vector_type(4)));

__device__ __forceinline__ unsigned short f2bf(float f) {
  unsigned int u = __builtin_bit_cast(unsigned int, f);
  u += 0x7fffu + ((u >> 16) & 1u);
  return (unsigned short)(u >> 16);
}

__device__ __forceinline__ short8 as_short8(uint4 u) {
  union { uint4 a; short8 b; } cv; cv.a = u; return cv.b;
}

// DMA one 8KB slab (64 rows x 128B) global->LDS, 16B/lane/instr, 8 instrs.
// Source pre-swizzled so lds[row j][16B-slot s] = global(j, s ^ (j&7)).
__device__ __forceinline__ void stage_slab(const unsigned short* gslab,
                                           unsigned short* lbase, int lane) {
  const int srcoff = ((lane >> 3) << 6) + (((lane & 7) ^ (lane >> 3)) << 3);  // shorts
  const unsigned short* gsrc = gslab + srcoff;
  #pragma unroll
  for (int k = 0; k < 8; ++k) {
    __builtin_amdgcn_global_load_lds(
        (const __attribute__((address_space(1))) unsigned int*)(gsrc + (k << 9)),
        (__attribute__((address_space(3))) unsigned int*)(lbase + (k << 9)),
        16, 0, 0);
  }
}

__global__ __launch_bounds__(256) void prep_w2s_kernel(const float* __restrict__ W2,
                                                       unsigned short* __restrict__ W2sB) {
  int g = blockIdx.x * 256 + threadIdx.x;      // each thread: 8 consecutive m
  int i = g >> 9, j = (g >> 3) & 63, m8 = (g & 7) << 3;
  const float* pa = &W2[((((i << 6) + j) << 6) + m8)];
  const float* pb = &W2[((((j << 6) + i) << 6) + m8)];
  float4 a0 = *(const float4*)pa, a1 = *(const float4*)(pa + 4);
  float4 b0 = *(const float4*)pb, b1 = *(const float4*)(pb + 4);
  short8 r;
  r[0] = (short)f2bf(a0.x + b0.x); r[1] = (short)f2bf(a0.y + b0.y);
  r[2] = (short)f2bf(a0.z + b0.z); r[3] = (short)f2bf(a0.w + b0.w);
  r[4] = (short)f2bf(a1.x + b1.x); r[5] = (short)f2bf(a1.y + b1.y);
  r[6] = (short)f2bf(a1.z + b1.z); r[7] = (short)f2bf(a1.w + b1.w);
  *(short8*)&W2sB[(size_t)g << 3] = r;
}

__global__ __launch_bounds__(512) void conn_kernel(
    const float* __restrict__ x, const float* __restrict__ v,
    const float* __restrict__ W1, const float* __restrict__ b1,
    const float* __restrict__ b2, const float* __restrict__ W3,
    const unsigned short* __restrict__ W2sB, float* __restrict__ out) {
  __shared__ __align__(16) unsigned short sAF[8][2][4096];  // per-wave slab dbuf, 128KB
  __shared__ __align__(16) unsigned short sKT[80 * 80];  // rows 0-63 = K^T, 64 = h, 65-79 = 0
  __shared__ __align__(16) float sg[64 * 68];            // g, stride 68 (f32x4-aligned stores)
  __shared__ __align__(16) float sh[64], sv[64], sx[64];

  // Overlays into sKT rows 0-63 (bytes 0..10239): dead once bf frags are
  // pinned; ext reads use only rows 64-79 (bytes >= 10240).
  float* const spq = (float*)sKT;          // [8][64] = 2048B
  float* const sq  = (float*)sKT + 512;    // 256B
  float* const szz = (float*)sKT + 576;    // [2][64] = 512B

  const int n = blockIdx.x, t = threadIdx.x;
  const int wv = t >> 6, lane = t & 63, ln15 = lane & 15, quad = lane >> 4;
  const int o8 = t >> 3, s8 = t & 7;

  if (t < 64) sx[t] = x[(n << 6) + t];
  else if (t < 128) sv[t - 64] = v[(n << 6) + (t - 64)];
  for (int e = t; e < 1280; e += 512) sKT[5120 + e] = 0;  // zero rows 64..79
  __syncthreads();

  // h[o] = tanh(b1[o] + sum_l sx[l] W1[o][l]); 8 lanes per output, shfl reduce
  {
    const float* w1r = &W1[(o8 << 6) + (s8 << 3)];
    float4 wa = *(const float4*)w1r, wb = *(const float4*)(w1r + 4);
    float4 xa = *(const float4*)&sx[s8 << 3], xb = *(const float4*)&sx[(s8 << 3) + 4];
    float acc = wa.x * xa.x + wa.y * xa.y + wa.z * xa.z + wa.w * xa.w
              + wb.x * xb.x + wb.y * xb.y + wb.z * xb.z + wb.w * xb.w;
    acc += __shfl_xor(acc, 1);
    acc += __shfl_xor(acc, 2);
    acc += __shfl_xor(acc, 4);
    if (s8 == 0) sh[o8] = tanhf(acc + b1[o8]);
  }
  __syncthreads();

  for (int e = t; e < 4096; e += 512) {
    int m = e & 63, l = e >> 6;
    float hm = sh[m];
    sKT[l * 80 + m] = f2bf((1.f - hm * hm) * W1[(m << 6) + l]);
  }
  if (t < 64) sKT[64 * 80 + t] = f2bf(sh[t]);
  __syncthreads();

  // sKT frags: tiles 0..3 dual-use (A for C2 row-tile / B for C1 col-tile).
  // Tile 4 (ext: h row) is reloaded from LDS per use (VGPR diet).
  short8 bf[4][2];
  #pragma unroll
  for (int tc = 0; tc < 4; ++tc)
    #pragma unroll
    for (int ks = 0; ks < 2; ++ks)
      bf[tc][ks] = *(const short8*)&sKT[(tc * 16 + ln15) * 80 + ks * 32 + quad * 8];

  float qacc[4] = {0.f, 0.f, 0.f, 0.f};

  // Wave wv owns i in [8*wv, 8*wv+8). Slab frags from LDS, swizzled reads:
  // element slot' = slot ^ (ln15&7); af[tc][1] address = [0] address ^ 32.
  const int f0 = (ln15 << 6) + (((quad ^ ln15) & 7) << 3);
  const int extoff = (64 + ln15) * 80 + quad * 8;   // h-row frag base (+32 for ks=1)
  unsigned short* const myAF = &sAF[wv][0][0];
  const unsigned short* const gbase = W2sB + ((size_t)(8 * wv) << 12);

  stage_slab(gbase, myAF, lane);   // prologue: slab 0 -> buf 0

  #pragma unroll 1
  for (int ii = 0; ii < 8; ++ii) {
    asm volatile("s_waitcnt vmcnt(0)" ::: "memory");   // buf[ii&1] DMA complete
    __builtin_amdgcn_sched_barrier(0);
    if (ii < 7)  // prefetch next slab into the other buffer; flies across compute
      stage_slab(gbase + ((size_t)(ii + 1) << 12), myAF + (((ii & 1) ^ 1) << 12), lane);

    const unsigned short* buf = myAF + ((ii & 1) << 12);
    uint4 af[4][2];
    #pragma unroll
    for (int tc = 0; tc < 4; ++tc) {
      af[tc][0] = *(const uint4*)&buf[(tc << 10) + f0];
      af[tc][1] = *(const uint4*)&buf[(tc << 10) + (f0 ^ 32)];
    }
    const int i = 8 * wv + ii;
    const float vi = sv[i];

    #pragma unroll
    for (int tr = 0; tr < 4; ++tr) {
      short8 a0 = as_short8(af[tr][0]), a1 = as_short8(af[tr][1]);
      // Batch all 8 independent 2-deep MFMA chains before any VALU consume:
      // cross-tc ILP hides MFMA latency (v1 structure, now within 128 regs).
      f32x4 c1[4], c2[4];
      #pragma unroll
      for (int tc = 0; tc < 4; ++tc) {
        f32x4 z4 = {0.f, 0.f, 0.f, 0.f};
        f32x4 u = __builtin_amdgcn_mfma_f32_16x16x32_bf16(a0, bf[tc][0], z4, 0, 0, 0);
        c1[tc]  = __builtin_amdgcn_mfma_f32_16x16x32_bf16(a1, bf[tc][1], u, 0, 0, 0);
        f32x4 w = __builtin_amdgcn_mfma_f32_16x16x32_bf16(bf[tr][0], as_short8(af[tc][0]), z4, 0, 0, 0);
        c2[tc]  = __builtin_amdgcn_mfma_f32_16x16x32_bf16(bf[tr][1], as_short8(af[tc][1]), w, 0, 0, 0);
      }
      {
        short8 e0 = *(const short8*)&sKT[extoff];
        short8 e1 = *(const short8*)&sKT[extoff + 32];
        f32x4 z4 = {0.f, 0.f, 0.f, 0.f};
        f32x4 u  = __builtin_amdgcn_mfma_f32_16x16x32_bf16(a0, e0, z4, 0, 0, 0);
        f32x4 ce = __builtin_amdgcn_mfma_f32_16x16x32_bf16(a1, e1, u, 0, 0, 0);
        if (ln15 == 0)  // g[i][j], j = 16*tr + 4*quad + r
          *(f32x4*)&sg[i * 68 + tr * 16 + quad * 4] = ce;
      }
      f32x4 svj = *(const f32x4*)&sv[tr * 16 + quad * 4];
      #pragma unroll
      for (int tc = 0; tc < 4; ++tc) {
        float s = 0.f;
        #pragma unroll
        for (int r = 0; r < 4; ++r) {
          float a = c1[tc][r];
          s = fmaf(a * a * c2[tc][r], svj[r], s);
        }
        qacc[tc] = fmaf(s, vi, qacc[tc]);
      }
    }
  }

  // reduce qacc over quads (rows j), publish per-wave partial q.
  // spq overlays sKT rows 0-63: dead for ALL waves during/after the i-loop
  // (only rows 64-79 are read as ext frags), so no barrier needed first.
  #pragma unroll
  for (int tc = 0; tc < 4; ++tc) {
    float s = qacc[tc];
    s += __shfl_xor(s, 16, 64);
    s += __shfl_xor(s, 32, 64);
    if (quad == 0) spq[(wv << 6) + tc * 16 + ln15] = s;
  }
  __syncthreads();  // first block-wide sync since setup

  for (int e = t; e < 4096; e += 512) {   // g += b2 + b2^T
    int r = e >> 6, c = e & 63;
    sg[r * 68 + c] += b2[(r << 6) + c] + b2[(c << 6) + r];
  }
  __syncthreads();

  if (t < 64) {
    float s = spq[t] + spq[64 + t] + spq[128 + t] + spq[192 + t]
            + spq[256 + t] + spq[320 + t] + spq[384 + t] + spq[448 + t];
    sq[t] = s;
    szz[t] = s / sg[t * 68 + t];   // Jacobi init (buffer 0)
  }
  __syncthreads();

  // Jacobi: z' = z + (q - g z)/diag; 8 lanes/row, double-buffered (1 barrier/iter)
  {
    const int row = o8;
    const float* grow = &sg[row * 68];
    const float dinv = 1.f / grow[row];
    const float qr = sq[row];
    int pb = 0;
    for (int it = 0; it < 20; ++it) {
      float p = 0.f;
      #pragma unroll
      for (int cc = 0; cc < 8; ++cc) {
        int c = (cc << 3) + s8;      // bank = (4*row + 8*cc + s8) % 32 -> 2-way (free)
        p += grow[c] * szz[(pb << 6) + c];
      }
      p += __shfl_xor(p, 1);
      p += __shfl_xor(p, 2);
      p += __shfl_xor(p, 4);
      if (s8 == 0) szz[((pb ^ 1) << 6) + row] = szz[(pb << 6) + row] + (qr - p) * dinv;
      __syncthreads();
      pb ^= 1;
    }
  }
  // 20 iters (even) -> final z in szz[0..63]

  // out[o] = sum_c v[c] W3[o][c] + 0.5 * sum_c z[c] W3[o][64+c]; 8 lanes/row
  {
    const float* w3r = &W3[o8 << 7];
    float4 wva = *(const float4*)&w3r[s8 << 3];
    float4 wvb = *(const float4*)&w3r[(s8 << 3) + 4];
    float4 wda = *(const float4*)&w3r[64 + (s8 << 3)];
    float4 wdb = *(const float4*)&w3r[64 + (s8 << 3) + 4];
    float4 va = *(const float4*)&sv[s8 << 3], vb = *(const float4*)&sv[(s8 << 3) + 4];
    float4 za = *(const float4*)&szz[s8 << 3], zb = *(const float4*)&szz[(s8 << 3) + 4];
    float acc = wva.x * va.x + wva.y * va.y + wva.z * va.z + wva.w * va.w
              + wvb.x * vb.x + wvb.y * vb.y + wvb.z * vb.z + wvb.w * vb.w
              + 0.5f * (wda.x * za.x + wda.y * za.y + wda.z * za.z + wda.w * za.w
                      + wdb.x * zb.x + wdb.y * zb.y + wdb.z * zb.z + wdb.w * zb.w);
    acc += __shfl_xor(acc, 1);
    acc += __shfl_xor(acc, 2);
    acc += __shfl_xor(acc, 4);
    if (s8 == 0) out[(n << 6) + o8] = acc;
  }
}

extern "C" void kernel_launch(void* const* d_in, const int* in_sizes, int n_in,
                              void* d_out, int out_size, void* d_ws, size_t ws_size,
                              hipStream_t stream) {
  (void)in_sizes; (void)n_in; (void)out_size; (void)ws_size;
  const float* x  = (const float*)d_in[1];
  const float* v  = (const float*)d_in[2];
  const float* W1 = (const float*)d_in[3];
  const float* b1 = (const float*)d_in[4];
  const float* W2 = (const float*)d_in[5];
  const float* b2 = (const float*)d_in[6];
  const float* W3 = (const float*)d_in[7];
  unsigned short* W2sB = (unsigned short*)d_ws;  // 64*64*64 bf16 = 512 KB

  hipLaunchKernelGGL(prep_w2s_kernel, dim3(128), dim3(256), 0, stream, W2, W2sB);
  hipLaunchKernelGGL(conn_kernel, dim3(256), dim3(512), 0, stream,
                     x, v, W1, b1, b2, W3, W2sB, (float*)d_out);
}

// Round 10
// 95.514 us; speedup vs baseline: 2.1879x; 1.0299x over previous
//
#include <hip/hip_runtime.h>
#include <math.h>
#include <stdint.h>

// n=256 samples, d=64, fp32 in/out. J-path bf16 MFMA.
//   K[m][l] = (1-h^2)[m] W1[m][l];  sKT[l][m] = K[m][l] (bf16), row 64 = h
//   W2sB[i][j][m] = bf16(W2[(i,j)][m] + W2[(j,i)][m])  (symmetric in i,j)
//   slab-frag af[t] and sKT-frag bf[t] are BOTH valid as A or B:
//     C1 = mfma(A=af[tr], B=bf[tc]) -> Ji[j][l];  C2 = mfma(A=bf[tr], B=af[tc])
//     -> Ji[l][j] at the SAME (lane,reg) => q in-register, no LDS transpose.
// Ledger: 512thr/128-VGPR diet (v7) = 2 waves/SIMD spill-free; DMA slab
//   dbuf (v8) neutral; c1/c2 MFMA batching (v9) -2.9us. VALUBusy/MfmaUtil
//   vs inst-count calibration => effective shader clock ~0.8-1GHz on this
//   bursty workload: instruction count + chained latency are the levers.
// v10: (a) packed-fp32 consume: per-tc math on float2 (v_pk_mul/fma) 13->8
//   ops; (b) Jacobi tail: single-wave register-matvec (lane r holds g-row
//   in 16 f32x4), z in LDS broadcast, 4-chain fma reduce - no shfl chain,
//   no per-iter barriers (in-order DS + lgkmcnt within one wave).
// v10 resubmit: round-9 run died on container acquisition (infra), kernel
//   never executed; theory untested, resubmitting unchanged.

typedef short short8 __attribute__((ext_vector_type(8)));
typedef float f32x4 __attribute__((ext_vector_type(4)));
typedef float f32x2 __attribute__((ext_vector_type(2)));

__device__ __forceinline__ unsigned short f2bf(float f) {
  unsigned int u = __builtin_bit_cast(unsigned int, f);
  u += 0x7fffu + ((u >> 16) & 1u);
  return (unsigned short)(u >> 16);
}

__device__ __forceinline__ short8 as_short8(uint4 u) {
  union { uint4 a; short8 b; } cv; cv.a = u; return cv.b;
}

// DMA one 8KB slab (64 rows x 128B) global->LDS, 16B/lane/instr, 8 instrs.
// Source pre-swizzled so lds[row j][16B-slot s] = global(j, s ^ (j&7)).
__device__ __forceinline__ void stage_slab(const unsigned short* gslab,
                                           unsigned short* lbase, int lane) {
  const int srcoff = ((lane >> 3) << 6) + (((lane & 7) ^ (lane >> 3)) << 3);  // shorts
  const unsigned short* gsrc = gslab + srcoff;
  #pragma unroll
  for (int k = 0; k < 8; ++k) {
    __builtin_amdgcn_global_load_lds(
        (const __attribute__((address_space(1))) unsigned int*)(gsrc + (k << 9)),
        (__attribute__((address_space(3))) unsigned int*)(lbase + (k << 9)),
        16, 0, 0);
  }
}

__global__ __launch_bounds__(256) void prep_w2s_kernel(const float* __restrict__ W2,
                                                       unsigned short* __restrict__ W2sB) {
  int g = blockIdx.x * 256 + threadIdx.x;      // each thread: 8 consecutive m
  int i = g >> 9, j = (g >> 3) & 63, m8 = (g & 7) << 3;
  const float* pa = &W2[((((i << 6) + j) << 6) + m8)];
  const float* pb = &W2[((((j << 6) + i) << 6) + m8)];
  float4 a0 = *(const float4*)pa, a1 = *(const float4*)(pa + 4);
  float4 b0 = *(const float4*)pb, b1 = *(const float4*)(pb + 4);
  short8 r;
  r[0] = (short)f2bf(a0.x + b0.x); r[1] = (short)f2bf(a0.y + b0.y);
  r[2] = (short)f2bf(a0.z + b0.z); r[3] = (short)f2bf(a0.w + b0.w);
  r[4] = (short)f2bf(a1.x + b1.x); r[5] = (short)f2bf(a1.y + b1.y);
  r[6] = (short)f2bf(a1.z + b1.z); r[7] = (short)f2bf(a1.w + b1.w);
  *(short8*)&W2sB[(size_t)g << 3] = r;
}

__global__ __launch_bounds__(512) void conn_kernel(
    const float* __restrict__ x, const float* __restrict__ v,
    const float* __restrict__ W1, const float* __restrict__ b1,
    const float* __restrict__ b2, const float* __restrict__ W3,
    const unsigned short* __restrict__ W2sB, float* __restrict__ out) {
  __shared__ __align__(16) unsigned short sAF[8][2][4096];  // per-wave slab dbuf, 128KB
  __shared__ __align__(16) unsigned short sKT[80 * 80];  // rows 0-63 = K^T, 64 = h, 65-79 = 0
  __shared__ __align__(16) float sg[64 * 68];            // g, stride 68 (f32x4-aligned stores)
  __shared__ __align__(16) float sh[64], sv[64], sx[64];

  // Overlays into sKT rows 0-63 (bytes 0..10239): dead once bf frags are
  // pinned; ext reads use only rows 64-79 (bytes >= 10240).
  float* const spq = (float*)sKT;          // [8][64] = 2048B
  float* const sq  = (float*)sKT + 512;    // 256B
  float* const szz = (float*)sKT + 576;    // [64] = 256B (z vector)

  const int n = blockIdx.x, t = threadIdx.x;
  const int wv = t >> 6, lane = t & 63, ln15 = lane & 15, quad = lane >> 4;
  const int o8 = t >> 3, s8 = t & 7;

  if (t < 64) sx[t] = x[(n << 6) + t];
  else if (t < 128) sv[t - 64] = v[(n << 6) + (t - 64)];
  for (int e = t; e < 1280; e += 512) sKT[5120 + e] = 0;  // zero rows 64..79
  __syncthreads();

  // h[o] = tanh(b1[o] + sum_l sx[l] W1[o][l]); 8 lanes per output, shfl reduce
  {
    const float* w1r = &W1[(o8 << 6) + (s8 << 3)];
    float4 wa = *(const float4*)w1r, wb = *(const float4*)(w1r + 4);
    float4 xa = *(const float4*)&sx[s8 << 3], xb = *(const float4*)&sx[(s8 << 3) + 4];
    float acc = wa.x * xa.x + wa.y * xa.y + wa.z * xa.z + wa.w * xa.w
              + wb.x * xb.x + wb.y * xb.y + wb.z * xb.z + wb.w * xb.w;
    acc += __shfl_xor(acc, 1);
    acc += __shfl_xor(acc, 2);
    acc += __shfl_xor(acc, 4);
    if (s8 == 0) sh[o8] = tanhf(acc + b1[o8]);
  }
  __syncthreads();

  for (int e = t; e < 4096; e += 512) {
    int m = e & 63, l = e >> 6;
    float hm = sh[m];
    sKT[l * 80 + m] = f2bf((1.f - hm * hm) * W1[(m << 6) + l]);
  }
  if (t < 64) sKT[64 * 80 + t] = f2bf(sh[t]);
  __syncthreads();

  // sKT frags: tiles 0..3 dual-use (A for C2 row-tile / B for C1 col-tile).
  // Tile 4 (ext: h row) is reloaded from LDS per use (VGPR diet).
  short8 bf[4][2];
  #pragma unroll
  for (int tc = 0; tc < 4; ++tc)
    #pragma unroll
    for (int ks = 0; ks < 2; ++ks)
      bf[tc][ks] = *(const short8*)&sKT[(tc * 16 + ln15) * 80 + ks * 32 + quad * 8];

  float qacc[4] = {0.f, 0.f, 0.f, 0.f};

  // Wave wv owns i in [8*wv, 8*wv+8). Slab frags from LDS, swizzled reads:
  // element slot' = slot ^ (ln15&7); af[tc][1] address = [0] address ^ 32.
  const int f0 = (ln15 << 6) + (((quad ^ ln15) & 7) << 3);
  const int extoff = (64 + ln15) * 80 + quad * 8;   // h-row frag base (+32 for ks=1)
  unsigned short* const myAF = &sAF[wv][0][0];
  const unsigned short* const gbase = W2sB + ((size_t)(8 * wv) << 12);

  stage_slab(gbase, myAF, lane);   // prologue: slab 0 -> buf 0

  #pragma unroll 1
  for (int ii = 0; ii < 8; ++ii) {
    asm volatile("s_waitcnt vmcnt(0)" ::: "memory");   // buf[ii&1] DMA complete
    __builtin_amdgcn_sched_barrier(0);
    if (ii < 7)  // prefetch next slab into the other buffer; flies across compute
      stage_slab(gbase + ((size_t)(ii + 1) << 12), myAF + (((ii & 1) ^ 1) << 12), lane);

    const unsigned short* buf = myAF + ((ii & 1) << 12);
    uint4 af[4][2];
    #pragma unroll
    for (int tc = 0; tc < 4; ++tc) {
      af[tc][0] = *(const uint4*)&buf[(tc << 10) + f0];
      af[tc][1] = *(const uint4*)&buf[(tc << 10) + (f0 ^ 32)];
    }
    const int i = 8 * wv + ii;
    const float vi = sv[i];

    #pragma unroll
    for (int tr = 0; tr < 4; ++tr) {
      short8 a0 = as_short8(af[tr][0]), a1 = as_short8(af[tr][1]);
      // Batch all 8 independent 2-deep MFMA chains before any VALU consume:
      // cross-tc ILP hides MFMA latency.
      f32x4 c1[4], c2[4];
      #pragma unroll
      for (int tc = 0; tc < 4; ++tc) {
        f32x4 z4 = {0.f, 0.f, 0.f, 0.f};
        f32x4 u = __builtin_amdgcn_mfma_f32_16x16x32_bf16(a0, bf[tc][0], z4, 0, 0, 0);
        c1[tc]  = __builtin_amdgcn_mfma_f32_16x16x32_bf16(a1, bf[tc][1], u, 0, 0, 0);
        f32x4 w = __builtin_amdgcn_mfma_f32_16x16x32_bf16(bf[tr][0], as_short8(af[tc][0]), z4, 0, 0, 0);
        c2[tc]  = __builtin_amdgcn_mfma_f32_16x16x32_bf16(bf[tr][1], as_short8(af[tc][1]), w, 0, 0, 0);
      }
      {
        short8 e0 = *(const short8*)&sKT[extoff];
        short8 e1 = *(const short8*)&sKT[extoff + 32];
        f32x4 z4 = {0.f, 0.f, 0.f, 0.f};
        f32x4 u  = __builtin_amdgcn_mfma_f32_16x16x32_bf16(a0, e0, z4, 0, 0, 0);
        f32x4 ce = __builtin_amdgcn_mfma_f32_16x16x32_bf16(a1, e1, u, 0, 0, 0);
        if (ln15 == 0)  // g[i][j], j = 16*tr + 4*quad + r
          *(f32x4*)&sg[i * 68 + tr * 16 + quad * 4] = ce;
      }
      // Packed-fp32 consume: per tc 6 pk ops + 2 scalar (vs 13 scalar).
      f32x4 svj = *(const f32x4*)&sv[tr * 16 + quad * 4];
      f32x2 vi2 = {vi, vi};
      f32x2 w01 = f32x2{svj[0], svj[1]} * vi2;
      f32x2 w23 = f32x2{svj[2], svj[3]} * vi2;
      #pragma unroll
      for (int tc = 0; tc < 4; ++tc) {
        f32x2 c101 = {c1[tc][0], c1[tc][1]}, c123 = {c1[tc][2], c1[tc][3]};
        f32x2 c201 = {c2[tc][0], c2[tc][1]}, c223 = {c2[tc][2], c2[tc][3]};
        f32x2 t01 = (c101 * c101) * c201;
        f32x2 t23 = (c123 * c123) * c223;
        f32x2 s2 = __builtin_elementwise_fma(t01, w01, t23 * w23);
        qacc[tc] += s2[0] + s2[1];
      }
    }
  }

  // reduce qacc over quads (rows j), publish per-wave partial q.
  // spq overlays sKT rows 0-63: dead for ALL waves during/after the i-loop
  // (only rows 64-79 are read as ext frags), so no barrier needed first.
  #pragma unroll
  for (int tc = 0; tc < 4; ++tc) {
    float s = qacc[tc];
    s += __shfl_xor(s, 16, 64);
    s += __shfl_xor(s, 32, 64);
    if (quad == 0) spq[(wv << 6) + tc * 16 + ln15] = s;
  }
  __syncthreads();  // first block-wide sync since setup

  for (int e = t; e < 4096; e += 512) {   // g += b2 + b2^T
    int r = e >> 6, c = e & 63;
    sg[r * 68 + c] += b2[(r << 6) + c] + b2[(c << 6) + r];
  }
  __syncthreads();

  if (t < 64) {
    float s = spq[t] + spq[64 + t] + spq[128 + t] + spq[192 + t]
            + spq[256 + t] + spq[320 + t] + spq[384 + t] + spq[448 + t];
    sq[t] = s;
    szz[t] = s / sg[t * 68 + t];   // Jacobi init
  }
  __syncthreads();

  // Jacobi: z' = z + (q - g z)/diag. Single-wave register-matvec:
  // lane r holds g-row r (16 f32x4, loaded once) + z_r; z vector in LDS
  // (broadcast reads, conflict-free). All reads of an iter issue before
  // the write (lockstep within one wave); in-order DS + lgkmcnt(0)
  // replaces barriers entirely.
  if (t < 64) {
    const float* grow = &sg[t * 68];
    f32x4 gr[16];
    #pragma unroll
    for (int cc = 0; cc < 16; ++cc) gr[cc] = *(const f32x4*)&grow[cc << 2];
    const float dinv = 1.f / grow[t];
    const float qr = sq[t];
    float zr = szz[t];
    #pragma unroll 1
    for (int it = 0; it < 20; ++it) {
      float p0 = 0.f, p1 = 0.f, p2 = 0.f, p3 = 0.f;
      #pragma unroll
      for (int cc = 0; cc < 16; ++cc) {
        f32x4 z4 = *(const f32x4*)&szz[cc << 2];
        p0 = fmaf(gr[cc][0], z4[0], p0);
        p1 = fmaf(gr[cc][1], z4[1], p1);
        p2 = fmaf(gr[cc][2], z4[2], p2);
        p3 = fmaf(gr[cc][3], z4[3], p3);
      }
      zr = zr + (qr - ((p0 + p1) + (p2 + p3))) * dinv;
      szz[t] = zr;
      asm volatile("s_waitcnt lgkmcnt(0)" ::: "memory");
      __builtin_amdgcn_sched_barrier(0);
    }
  }
  __syncthreads();

  // out[o] = sum_c v[c] W3[o][c] + 0.5 * sum_c z[c] W3[o][64+c]; 8 lanes/row
  {
    const float* w3r = &W3[o8 << 7];
    float4 wva = *(const float4*)&w3r[s8 << 3];
    float4 wvb = *(const float4*)&w3r[(s8 << 3) + 4];
    float4 wda = *(const float4*)&w3r[64 + (s8 << 3)];
    float4 wdb = *(const float4*)&w3r[64 + (s8 << 3) + 4];
    float4 va = *(const float4*)&sv[s8 << 3], vb = *(const float4*)&sv[(s8 << 3) + 4];
    float4 za = *(const float4*)&szz[s8 << 3], zb = *(const float4*)&szz[(s8 << 3) + 4];
    float acc = wva.x * va.x + wva.y * va.y + wva.z * va.z + wva.w * va.w
              + wvb.x * vb.x + wvb.y * vb.y + wvb.z * vb.z + wvb.w * vb.w
              + 0.5f * (wda.x * za.x + wda.y * za.y + wda.z * za.z + wda.w * za.w
                      + wdb.x * zb.x + wdb.y * zb.y + wdb.z * zb.z + wdb.w * zb.w);
    acc += __shfl_xor(acc, 1);
    acc += __shfl_xor(acc, 2);
    acc += __shfl_xor(acc, 4);
    if (s8 == 0) out[(n << 6) + o8] = acc;
  }
}

extern "C" void kernel_launch(void* const* d_in, const int* in_sizes, int n_in,
                              void* d_out, int out_size, void* d_ws, size_t ws_size,
                              hipStream_t stream) {
  (void)in_sizes; (void)n_in; (void)out_size; (void)ws_size;
  const float* x  = (const float*)d_in[1];
  const float* v  = (const float*)d_in[2];
  const float* W1 = (const float*)d_in[3];
  const float* b1 = (const float*)d_in[4];
  const float* W2 = (const float*)d_in[5];
  const float* b2 = (const float*)d_in[6];
  const float* W3 = (const float*)d_in[7];
  unsigned short* W2sB = (unsigned short*)d_ws;  // 64*64*64 bf16 = 512 KB

  hipLaunchKernelGGL(prep_w2s_kernel, dim3(128), dim3(256), 0, stream, W2, W2sB);
  hipLaunchKernelGGL(conn_kernel, dim3(256), dim3(512), 0, stream,
                     x, v, W1, b1, b2, W3, W2sB, (float*)d_out);
}

// Round 11
// 93.223 us; speedup vs baseline: 2.2417x; 1.0246x over previous
//
#include <hip/hip_runtime.h>
#include <math.h>
#include <stdint.h>

// n=256 samples, d=64, fp32 in/out. J-path bf16 MFMA.
//   K[m][l] = (1-h^2)[m] W1[m][l];  sKT[l][m] = K[m][l] (bf16), row 64 = h
//   W2sB[i][j][m] = bf16(W2[(i,j)][m] + W2[(j,i)][m])  (symmetric in i,j)
//   slab-frag af[t] and sKT-frag bf[t] are BOTH valid as A or B:
//     C1 = mfma(A=af[tr], B=bf[tc]) -> Ji[j][l];  C2 = mfma(A=bf[tr], B=af[tc])
//     -> Ji[l][j] at the SAME (lane,reg) => q in-register, no LDS transpose.
// Ledger: 512thr/128-VGPR diet (v7) 2 waves/SIMD spill-free; DMA dbuf (v8)
//   neutral; MFMA batching (v9) -2.9us; pk-consume + 1-wave Jacobi (v10)
//   -2.9us. Calibration: MfmaUtil vs static count => effective clock
//   ~810MHz on this bursty workload; conn ~39.5us vs ~13k-cycle i-loop
//   floor => serial phases dominate the residual.
// v11: (a) Jacobi tail: 8 chains of 8 (32cy chains), NO per-iter lgkmcnt
//   drain (in-wave DS is in-order), 20->14 iters (rho(D^-1 E)~0.38 =>
//   0.38^14 ~ 1e-6 << bf16-J floor ~1e-3); (b) coalesce setup: prep also
//   emits W1T and b2s=b2+b2^T so conn's sKT-build and g-symmetrize read
//   contiguous; (c) consume: fma folded into f32x2 qacc2 (6 pk/tc).

typedef short short8 __attribute__((ext_vector_type(8)));
typedef float f32x4 __attribute__((ext_vector_type(4)));
typedef float f32x2 __attribute__((ext_vector_type(2)));

__device__ __forceinline__ unsigned short f2bf(float f) {
  unsigned int u = __builtin_bit_cast(unsigned int, f);
  u += 0x7fffu + ((u >> 16) & 1u);
  return (unsigned short)(u >> 16);
}

__device__ __forceinline__ short8 as_short8(uint4 u) {
  union { uint4 a; short8 b; } cv; cv.a = u; return cv.b;
}

// DMA one 8KB slab (64 rows x 128B) global->LDS, 16B/lane/instr, 8 instrs.
// Source pre-swizzled so lds[row j][16B-slot s] = global(j, s ^ (j&7)).
__device__ __forceinline__ void stage_slab(const unsigned short* gslab,
                                           unsigned short* lbase, int lane) {
  const int srcoff = ((lane >> 3) << 6) + (((lane & 7) ^ (lane >> 3)) << 3);  // shorts
  const unsigned short* gsrc = gslab + srcoff;
  #pragma unroll
  for (int k = 0; k < 8; ++k) {
    __builtin_amdgcn_global_load_lds(
        (const __attribute__((address_space(1))) unsigned int*)(gsrc + (k << 9)),
        (__attribute__((address_space(3))) unsigned int*)(lbase + (k << 9)),
        16, 0, 0);
  }
}

// Blocks 0-127: W2sB (bf16 symmetrized W2 slabs). Block 128: W1T (f32).
// Block 129: b2s = b2 + b2^T (f32). All sample-invariant.
__global__ __launch_bounds__(256) void prep_kernel(
    const float* __restrict__ W2, const float* __restrict__ W1,
    const float* __restrict__ b2, unsigned short* __restrict__ W2sB,
    float* __restrict__ W1T, float* __restrict__ b2s) {
  const int b = blockIdx.x;
  if (b < 128) {
    int g = b * 256 + threadIdx.x;      // each thread: 8 consecutive m
    int i = g >> 9, j = (g >> 3) & 63, m8 = (g & 7) << 3;
    const float* pa = &W2[((((i << 6) + j) << 6) + m8)];
    const float* pb = &W2[((((j << 6) + i) << 6) + m8)];
    float4 a0 = *(const float4*)pa, a1 = *(const float4*)(pa + 4);
    float4 b0 = *(const float4*)pb, b1 = *(const float4*)(pb + 4);
    short8 r;
    r[0] = (short)f2bf(a0.x + b0.x); r[1] = (short)f2bf(a0.y + b0.y);
    r[2] = (short)f2bf(a0.z + b0.z); r[3] = (short)f2bf(a0.w + b0.w);
    r[4] = (short)f2bf(a1.x + b1.x); r[5] = (short)f2bf(a1.y + b1.y);
    r[6] = (short)f2bf(a1.z + b1.z); r[7] = (short)f2bf(a1.w + b1.w);
    *(short8*)&W2sB[(size_t)g << 3] = r;
  } else if (b == 128) {
    for (int e = threadIdx.x; e < 4096; e += 256) {
      int l = e >> 6, m = e & 63;
      W1T[e] = W1[(m << 6) + l];              // W1T[l][m] = W1[m][l]
    }
  } else {
    for (int e = threadIdx.x; e < 4096; e += 256) {
      int r = e >> 6, c = e & 63;
      b2s[e] = b2[(r << 6) + c] + b2[(c << 6) + r];
    }
  }
}

__global__ __launch_bounds__(512) void conn_kernel(
    const float* __restrict__ x, const float* __restrict__ v,
    const float* __restrict__ W1, const float* __restrict__ b1,
    const float* __restrict__ W3, const unsigned short* __restrict__ W2sB,
    const float* __restrict__ W1T, const float* __restrict__ b2s,
    float* __restrict__ out) {
  __shared__ __align__(16) unsigned short sAF[8][2][4096];  // per-wave slab dbuf, 128KB
  __shared__ __align__(16) unsigned short sKT[80 * 80];  // rows 0-63 = K^T, 64 = h, 65-79 = 0
  __shared__ __align__(16) float sg[64 * 68];            // g, stride 68 (f32x4-aligned stores)
  __shared__ __align__(16) float sh[64], sv[64], sx[64];

  // Overlays into sKT rows 0-63 (bytes 0..10239): dead once bf frags are
  // pinned; ext reads use only rows 64-79 (bytes >= 10240).
  float* const spq = (float*)sKT;          // [8][64] = 2048B
  float* const sq  = (float*)sKT + 512;    // 256B
  float* const szz = (float*)sKT + 576;    // [64] = 256B (z vector)

  const int n = blockIdx.x, t = threadIdx.x;
  const int wv = t >> 6, lane = t & 63, ln15 = lane & 15, quad = lane >> 4;
  const int o8 = t >> 3, s8 = t & 7;

  if (t < 64) sx[t] = x[(n << 6) + t];
  else if (t < 128) sv[t - 64] = v[(n << 6) + (t - 64)];
  for (int e = t; e < 1280; e += 512) sKT[5120 + e] = 0;  // zero rows 64..79
  __syncthreads();

  // h[o] = tanh(b1[o] + sum_l sx[l] W1[o][l]); 8 lanes per output, shfl reduce
  {
    const float* w1r = &W1[(o8 << 6) + (s8 << 3)];
    float4 wa = *(const float4*)w1r, wb = *(const float4*)(w1r + 4);
    float4 xa = *(const float4*)&sx[s8 << 3], xb = *(const float4*)&sx[(s8 << 3) + 4];
    float acc = wa.x * xa.x + wa.y * xa.y + wa.z * xa.z + wa.w * xa.w
              + wb.x * xb.x + wb.y * xb.y + wb.z * xb.z + wb.w * xb.w;
    acc += __shfl_xor(acc, 1);
    acc += __shfl_xor(acc, 2);
    acc += __shfl_xor(acc, 4);
    if (s8 == 0) sh[o8] = tanhf(acc + b1[o8]);
  }
  __syncthreads();

  for (int e = t; e < 4096; e += 512) {   // coalesced: W1T[l*64+m]
    int m = e & 63, l = e >> 6;
    float hm = sh[m];
    sKT[l * 80 + m] = f2bf((1.f - hm * hm) * W1T[e]);
  }
  if (t < 64) sKT[64 * 80 + t] = f2bf(sh[t]);
  __syncthreads();

  // sKT frags: tiles 0..3 dual-use (A for C2 row-tile / B for C1 col-tile).
  // Tile 4 (ext: h row) is reloaded from LDS per use (VGPR diet).
  short8 bf[4][2];
  #pragma unroll
  for (int tc = 0; tc < 4; ++tc)
    #pragma unroll
    for (int ks = 0; ks < 2; ++ks)
      bf[tc][ks] = *(const short8*)&sKT[(tc * 16 + ln15) * 80 + ks * 32 + quad * 8];

  f32x2 qacc2[4] = {{0.f, 0.f}, {0.f, 0.f}, {0.f, 0.f}, {0.f, 0.f}};

  // Wave wv owns i in [8*wv, 8*wv+8). Slab frags from LDS, swizzled reads:
  // element slot' = slot ^ (ln15&7); af[tc][1] address = [0] address ^ 32.
  const int f0 = (ln15 << 6) + (((quad ^ ln15) & 7) << 3);
  const int extoff = (64 + ln15) * 80 + quad * 8;   // h-row frag base (+32 for ks=1)
  unsigned short* const myAF = &sAF[wv][0][0];
  const unsigned short* const gbase = W2sB + ((size_t)(8 * wv) << 12);

  stage_slab(gbase, myAF, lane);   // prologue: slab 0 -> buf 0

  #pragma unroll 1
  for (int ii = 0; ii < 8; ++ii) {
    asm volatile("s_waitcnt vmcnt(0)" ::: "memory");   // buf[ii&1] DMA complete
    __builtin_amdgcn_sched_barrier(0);
    if (ii < 7)  // prefetch next slab into the other buffer; flies across compute
      stage_slab(gbase + ((size_t)(ii + 1) << 12), myAF + (((ii & 1) ^ 1) << 12), lane);

    const unsigned short* buf = myAF + ((ii & 1) << 12);
    uint4 af[4][2];
    #pragma unroll
    for (int tc = 0; tc < 4; ++tc) {
      af[tc][0] = *(const uint4*)&buf[(tc << 10) + f0];
      af[tc][1] = *(const uint4*)&buf[(tc << 10) + (f0 ^ 32)];
    }
    const int i = 8 * wv + ii;
    const float vi = sv[i];

    #pragma unroll
    for (int tr = 0; tr < 4; ++tr) {
      short8 a0 = as_short8(af[tr][0]), a1 = as_short8(af[tr][1]);
      // Batch all 8 independent 2-deep MFMA chains before any VALU consume:
      // cross-tc ILP hides MFMA latency.
      f32x4 c1[4], c2[4];
      #pragma unroll
      for (int tc = 0; tc < 4; ++tc) {
        f32x4 z4 = {0.f, 0.f, 0.f, 0.f};
        f32x4 u = __builtin_amdgcn_mfma_f32_16x16x32_bf16(a0, bf[tc][0], z4, 0, 0, 0);
        c1[tc]  = __builtin_amdgcn_mfma_f32_16x16x32_bf16(a1, bf[tc][1], u, 0, 0, 0);
        f32x4 w = __builtin_amdgcn_mfma_f32_16x16x32_bf16(bf[tr][0], as_short8(af[tc][0]), z4, 0, 0, 0);
        c2[tc]  = __builtin_amdgcn_mfma_f32_16x16x32_bf16(bf[tr][1], as_short8(af[tc][1]), w, 0, 0, 0);
      }
      {
        short8 e0 = *(const short8*)&sKT[extoff];
        short8 e1 = *(const short8*)&sKT[extoff + 32];
        f32x4 z4 = {0.f, 0.f, 0.f, 0.f};
        f32x4 u  = __builtin_amdgcn_mfma_f32_16x16x32_bf16(a0, e0, z4, 0, 0, 0);
        f32x4 ce = __builtin_amdgcn_mfma_f32_16x16x32_bf16(a1, e1, u, 0, 0, 0);
        if (ln15 == 0)  // g[i][j], j = 16*tr + 4*quad + r
          *(f32x4*)&sg[i * 68 + tr * 16 + quad * 4] = ce;
      }
      // Packed-fp32 consume: per tc 6 pk ops, fma folded into qacc2.
      f32x4 svj = *(const f32x4*)&sv[tr * 16 + quad * 4];
      f32x2 vi2 = {vi, vi};
      f32x2 w01 = f32x2{svj[0], svj[1]} * vi2;
      f32x2 w23 = f32x2{svj[2], svj[3]} * vi2;
      #pragma unroll
      for (int tc = 0; tc < 4; ++tc) {
        f32x2 c101 = {c1[tc][0], c1[tc][1]}, c123 = {c1[tc][2], c1[tc][3]};
        f32x2 c201 = {c2[tc][0], c2[tc][1]}, c223 = {c2[tc][2], c2[tc][3]};
        f32x2 t01 = (c101 * c101) * c201;
        f32x2 t23 = (c123 * c123) * c223;
        qacc2[tc] = __builtin_elementwise_fma(t01, w01, qacc2[tc]);
        qacc2[tc] = __builtin_elementwise_fma(t23, w23, qacc2[tc]);
      }
    }
  }

  // reduce qacc over quads (rows j), publish per-wave partial q.
  // spq overlays sKT rows 0-63: dead for ALL waves during/after the i-loop
  // (only rows 64-79 are read as ext frags), so no barrier needed first.
  #pragma unroll
  for (int tc = 0; tc < 4; ++tc) {
    float s = qacc2[tc][0] + qacc2[tc][1];
    s += __shfl_xor(s, 16, 64);
    s += __shfl_xor(s, 32, 64);
    if (quad == 0) spq[(wv << 6) + tc * 16 + ln15] = s;
  }
  __syncthreads();  // first block-wide sync since setup

  for (int e = t; e < 4096; e += 512)     // g += b2 + b2^T (precomputed, coalesced)
    sg[(e >> 6) * 68 + (e & 63)] += b2s[e];
  __syncthreads();

  if (t < 64) {
    float s = spq[t] + spq[64 + t] + spq[128 + t] + spq[192 + t]
            + spq[256 + t] + spq[320 + t] + spq[384 + t] + spq[448 + t];
    sq[t] = s;
    szz[t] = s / sg[t * 68 + t];   // Jacobi init
  }
  __syncthreads();

  // Jacobi: z' = z + (q - g z)/diag. Single-wave register-matvec:
  // lane r holds g-row r (16 f32x4, loaded once); z in LDS (broadcast).
  // 8 independent 8-deep fma chains; NO per-iter drain (in-wave DS ops
  // execute in order, so next iter's reads see this iter's write).
  // 14 iters: rho(D^-1 E)~0.38 => residual ~1e-6 << bf16-J floor.
  if (t < 64) {
    const float* grow = &sg[t * 68];
    f32x4 gr[16];
    #pragma unroll
    for (int cc = 0; cc < 16; ++cc) gr[cc] = *(const f32x4*)&grow[cc << 2];
    const float dinv = 1.f / grow[t];
    const float qr = sq[t];
    float zr = szz[t];
    #pragma unroll 1
    for (int it = 0; it < 14; ++it) {
      float p[8];
      #pragma unroll
      for (int cc = 0; cc < 8; ++cc) {
        f32x4 za_ = *(const f32x4*)&szz[cc << 3];
        f32x4 zb_ = *(const f32x4*)&szz[(cc << 3) + 4];
        f32x4 ga = gr[cc << 1], gb = gr[(cc << 1) + 1];
        float s = ga[0] * za_[0];
        s = fmaf(ga[1], za_[1], s);
        s = fmaf(ga[2], za_[2], s);
        s = fmaf(ga[3], za_[3], s);
        s = fmaf(gb[0], zb_[0], s);
        s = fmaf(gb[1], zb_[1], s);
        s = fmaf(gb[2], zb_[2], s);
        s = fmaf(gb[3], zb_[3], s);
        p[cc] = s;
      }
      float r4 = ((p[0] + p[1]) + (p[2] + p[3])) + ((p[4] + p[5]) + (p[6] + p[7]));
      zr = zr + (qr - r4) * dinv;
      szz[t] = zr;
      __builtin_amdgcn_sched_barrier(0);
    }
  }
  __syncthreads();

  // out[o] = sum_c v[c] W3[o][c] + 0.5 * sum_c z[c] W3[o][64+c]; 8 lanes/row
  {
    const float* w3r = &W3[o8 << 7];
    float4 wva = *(const float4*)&w3r[s8 << 3];
    float4 wvb = *(const float4*)&w3r[(s8 << 3) + 4];
    float4 wda = *(const float4*)&w3r[64 + (s8 << 3)];
    float4 wdb = *(const float4*)&w3r[64 + (s8 << 3) + 4];
    float4 va = *(const float4*)&sv[s8 << 3], vb = *(const float4*)&sv[(s8 << 3) + 4];
    float4 za = *(const float4*)&szz[s8 << 3], zb = *(const float4*)&szz[(s8 << 3) + 4];
    float acc = wva.x * va.x + wva.y * va.y + wva.z * va.z + wva.w * va.w
              + wvb.x * vb.x + wvb.y * vb.y + wvb.z * vb.z + wvb.w * vb.w
              + 0.5f * (wda.x * za.x + wda.y * za.y + wda.z * za.z + wda.w * za.w
                      + wdb.x * zb.x + wdb.y * zb.y + wdb.z * zb.z + wdb.w * zb.w);
    acc += __shfl_xor(acc, 1);
    acc += __shfl_xor(acc, 2);
    acc += __shfl_xor(acc, 4);
    if (s8 == 0) out[(n << 6) + o8] = acc;
  }
}

extern "C" void kernel_launch(void* const* d_in, const int* in_sizes, int n_in,
                              void* d_out, int out_size, void* d_ws, size_t ws_size,
                              hipStream_t stream) {
  (void)in_sizes; (void)n_in; (void)out_size; (void)ws_size;
  const float* x  = (const float*)d_in[1];
  const float* v  = (const float*)d_in[2];
  const float* W1 = (const float*)d_in[3];
  const float* b1 = (const float*)d_in[4];
  const float* W2 = (const float*)d_in[5];
  const float* b2 = (const float*)d_in[6];
  const float* W3 = (const float*)d_in[7];
  unsigned short* W2sB = (unsigned short*)d_ws;       // 64*64*64 bf16 = 512 KB
  float* W1T = (float*)((char*)d_ws + (512 << 10));   // 16 KB
  float* b2s = W1T + 4096;                            // 16 KB

  hipLaunchKernelGGL(prep_kernel, dim3(130), dim3(256), 0, stream,
                     W2, W1, b2, W2sB, W1T, b2s);
  hipLaunchKernelGGL(conn_kernel, dim3(256), dim3(512), 0, stream,
                     x, v, W1, b1, W3, W2sB, W1T, b2s, (float*)d_out);
}

// Round 12
// 93.089 us; speedup vs baseline: 2.2449x; 1.0014x over previous
//
#include <hip/hip_runtime.h>
#include <math.h>
#include <stdint.h>

// n=256 samples, d=64, fp32 in/out. J-path bf16 MFMA.
//   K[m][l] = (1-h^2)[m] W1[m][l];  sKT[l][m] = K[m][l] (bf16), row 64 = h
//   W2sB[i][j][m] = bf16(W2[(i,j)][m] + W2[(j,i)][m])  (symmetric in i,j)
//   slab-frag af[t] and sKT-frag bf[t] are BOTH valid as A or B:
//     C1 = mfma(A=af[tr], B=bf[tc]) -> Ji[j][l];  C2 = mfma(A=bf[tr], B=af[tc])
//     -> Ji[l][j] at the SAME (lane,reg) => q in-register, no LDS transpose.
// Ledger: 512thr/128-VGPR diet (v7) 2 waves/SIMD spill-free; DMA dbuf (v8)
//   NEUTRAL vs direct loads; MFMA batching (v9) -2.9us; pk-consume +
//   1-wave Jacobi (v10) -2.9us; W1T/b2s precompute + 8x8 Jacobi chains +
//   14 iters (v11) -2.3us. Effective clock ~810MHz (bursty) => instruction
//   count + chained latency are the levers. Occupancy routes exhausted:
//   VGPR cap is block-size-keyed (256->168, 512->128, 1024->64, attributes
//   can't raise it); grid pinned at 256; A/B split costs ~9us (v6).
// v12: (a) drop DMA/sAF (v8 proved neutral): direct global uint4 af loads,
//   -8 DMA + vmcnt + sched_barrier per ii, -128KB LDS; (b) Jacobi 14->10
//   (residual ~1e-5 << bf16-J floor ~1e-3); (c) hoist v@W3[:, :64] before
//   Jacobi (overlaps W3 loads with b2s/Jacobi); (d) exp2f-based tanh in
//   the h phase (hw v_exp_f32, ~1e-7 err << bf16 rounding of h).

typedef short short8 __attribute__((ext_vector_type(8)));
typedef float f32x4 __attribute__((ext_vector_type(4)));
typedef float f32x2 __attribute__((ext_vector_type(2)));

__device__ __forceinline__ unsigned short f2bf(float f) {
  unsigned int u = __builtin_bit_cast(unsigned int, f);
  u += 0x7fffu + ((u >> 16) & 1u);
  return (unsigned short)(u >> 16);
}

__device__ __forceinline__ short8 as_short8(uint4 u) {
  union { uint4 a; short8 b; } cv; cv.a = u; return cv.b;
}

// Blocks 0-127: W2sB (bf16 symmetrized W2 slabs). Block 128: W1T (f32).
// Block 129: b2s = b2 + b2^T (f32). All sample-invariant.
__global__ __launch_bounds__(256) void prep_kernel(
    const float* __restrict__ W2, const float* __restrict__ W1,
    const float* __restrict__ b2, unsigned short* __restrict__ W2sB,
    float* __restrict__ W1T, float* __restrict__ b2s) {
  const int b = blockIdx.x;
  if (b < 128) {
    int g = b * 256 + threadIdx.x;      // each thread: 8 consecutive m
    int i = g >> 9, j = (g >> 3) & 63, m8 = (g & 7) << 3;
    const float* pa = &W2[((((i << 6) + j) << 6) + m8)];
    const float* pb = &W2[((((j << 6) + i) << 6) + m8)];
    float4 a0 = *(const float4*)pa, a1 = *(const float4*)(pa + 4);
    float4 b0 = *(const float4*)pb, b1 = *(const float4*)(pb + 4);
    short8 r;
    r[0] = (short)f2bf(a0.x + b0.x); r[1] = (short)f2bf(a0.y + b0.y);
    r[2] = (short)f2bf(a0.z + b0.z); r[3] = (short)f2bf(a0.w + b0.w);
    r[4] = (short)f2bf(a1.x + b1.x); r[5] = (short)f2bf(a1.y + b1.y);
    r[6] = (short)f2bf(a1.z + b1.z); r[7] = (short)f2bf(a1.w + b1.w);
    *(short8*)&W2sB[(size_t)g << 3] = r;
  } else if (b == 128) {
    for (int e = threadIdx.x; e < 4096; e += 256) {
      int l = e >> 6, m = e & 63;
      W1T[e] = W1[(m << 6) + l];              // W1T[l][m] = W1[m][l]
    }
  } else {
    for (int e = threadIdx.x; e < 4096; e += 256) {
      int r = e >> 6, c = e & 63;
      b2s[e] = b2[(r << 6) + c] + b2[(c << 6) + r];
    }
  }
}

__global__ __launch_bounds__(512) void conn_kernel(
    const float* __restrict__ x, const float* __restrict__ v,
    const float* __restrict__ W1, const float* __restrict__ b1,
    const float* __restrict__ W3, const unsigned short* __restrict__ W2sB,
    const float* __restrict__ W1T, const float* __restrict__ b2s,
    float* __restrict__ out) {
  __shared__ __align__(16) unsigned short sKT[80 * 80];  // rows 0-63 = K^T, 64 = h, 65-79 = 0
  __shared__ __align__(16) float sg[64 * 68];            // g, stride 68 (f32x4-aligned stores)
  __shared__ __align__(16) float sh[64], sv[64], sx[64];

  // Overlays into sKT rows 0-63 (bytes 0..10239): dead once bf frags are
  // pinned; ext reads use only rows 64-79 (bytes >= 10240).
  float* const spq = (float*)sKT;          // [8][64] = 2048B
  float* const sq  = (float*)sKT + 512;    // 256B
  float* const szz = (float*)sKT + 576;    // [64] = 256B (z vector)

  const int n = blockIdx.x, t = threadIdx.x;
  const int wv = t >> 6, lane = t & 63, ln15 = lane & 15, quad = lane >> 4;
  const int o8 = t >> 3, s8 = t & 7;

  if (t < 64) sx[t] = x[(n << 6) + t];
  else if (t < 128) sv[t - 64] = v[(n << 6) + (t - 64)];
  for (int e = t; e < 1280; e += 512) sKT[5120 + e] = 0;  // zero rows 64..79
  __syncthreads();

  // h[o] = tanh(b1[o] + sum_l sx[l] W1[o][l]); 8 lanes per output, shfl reduce
  {
    const float* w1r = &W1[(o8 << 6) + (s8 << 3)];
    float4 wa = *(const float4*)w1r, wb = *(const float4*)(w1r + 4);
    float4 xa = *(const float4*)&sx[s8 << 3], xb = *(const float4*)&sx[(s8 << 3) + 4];
    float acc = wa.x * xa.x + wa.y * xa.y + wa.z * xa.z + wa.w * xa.w
              + wb.x * xb.x + wb.y * xb.y + wb.z * xb.z + wb.w * xb.w;
    acc += __shfl_xor(acc, 1);
    acc += __shfl_xor(acc, 2);
    acc += __shfl_xor(acc, 4);
    if (s8 == 0) {
      float a = acc + b1[o8];
      a = fminf(10.f, fmaxf(-10.f, a));          // tanh(10)=1-4e-9, safe clamp
      float e2 = exp2f(a * 2.8853900817779268f); // e^(2a) via hw v_exp_f32
      sh[o8] = (e2 - 1.f) / (e2 + 1.f);
    }
  }
  __syncthreads();

  for (int e = t; e < 4096; e += 512) {   // coalesced: W1T[l*64+m]
    int m = e & 63, l = e >> 6;
    float hm = sh[m];
    sKT[l * 80 + m] = f2bf((1.f - hm * hm) * W1T[e]);
  }
  if (t < 64) sKT[64 * 80 + t] = f2bf(sh[t]);
  __syncthreads();

  // sKT frags: tiles 0..3 dual-use (A for C2 row-tile / B for C1 col-tile).
  // Tile 4 (ext: h row) is reloaded from LDS per use (VGPR diet).
  short8 bf[4][2];
  #pragma unroll
  for (int tc = 0; tc < 4; ++tc)
    #pragma unroll
    for (int ks = 0; ks < 2; ++ks)
      bf[tc][ks] = *(const short8*)&sKT[(tc * 16 + ln15) * 80 + ks * 32 + quad * 8];

  f32x2 qacc2[4] = {{0.f, 0.f}, {0.f, 0.f}, {0.f, 0.f}, {0.f, 0.f}};

  // Wave wv owns i in [8*wv, 8*wv+8). Direct global uint4 frag loads
  // (L2-resident; DMA staging measured neutral in v8).
  const int foff = (ln15 << 6) + quad * 8;
  const int extoff = (64 + ln15) * 80 + quad * 8;   // h-row frag base (+32 for ks=1)
  const unsigned short* const gbase = W2sB + ((size_t)(8 * wv) << 12);

  #pragma unroll 1
  for (int ii = 0; ii < 8; ++ii) {
    const unsigned short* sp = gbase + ((size_t)ii << 12);
    uint4 af[4][2];
    #pragma unroll
    for (int tc = 0; tc < 4; ++tc) {
      af[tc][0] = *(const uint4*)(sp + (tc << 10) + foff);
      af[tc][1] = *(const uint4*)(sp + (tc << 10) + foff + 32);
    }
    const int i = 8 * wv + ii;
    const float vi = sv[i];

    #pragma unroll
    for (int tr = 0; tr < 4; ++tr) {
      short8 a0 = as_short8(af[tr][0]), a1 = as_short8(af[tr][1]);
      // Batch all 8 independent 2-deep MFMA chains before any VALU consume:
      // cross-tc ILP hides MFMA latency.
      f32x4 c1[4], c2[4];
      #pragma unroll
      for (int tc = 0; tc < 4; ++tc) {
        f32x4 z4 = {0.f, 0.f, 0.f, 0.f};
        f32x4 u = __builtin_amdgcn_mfma_f32_16x16x32_bf16(a0, bf[tc][0], z4, 0, 0, 0);
        c1[tc]  = __builtin_amdgcn_mfma_f32_16x16x32_bf16(a1, bf[tc][1], u, 0, 0, 0);
        f32x4 w = __builtin_amdgcn_mfma_f32_16x16x32_bf16(bf[tr][0], as_short8(af[tc][0]), z4, 0, 0, 0);
        c2[tc]  = __builtin_amdgcn_mfma_f32_16x16x32_bf16(bf[tr][1], as_short8(af[tc][1]), w, 0, 0, 0);
      }
      {
        short8 e0 = *(const short8*)&sKT[extoff];
        short8 e1 = *(const short8*)&sKT[extoff + 32];
        f32x4 z4 = {0.f, 0.f, 0.f, 0.f};
        f32x4 u  = __builtin_amdgcn_mfma_f32_16x16x32_bf16(a0, e0, z4, 0, 0, 0);
        f32x4 ce = __builtin_amdgcn_mfma_f32_16x16x32_bf16(a1, e1, u, 0, 0, 0);
        if (ln15 == 0)  // g[i][j], j = 16*tr + 4*quad + r
          *(f32x4*)&sg[i * 68 + tr * 16 + quad * 4] = ce;
      }
      // Packed-fp32 consume: per tc 6 pk ops, fma folded into qacc2.
      f32x4 svj = *(const f32x4*)&sv[tr * 16 + quad * 4];
      f32x2 vi2 = {vi, vi};
      f32x2 w01 = f32x2{svj[0], svj[1]} * vi2;
      f32x2 w23 = f32x2{svj[2], svj[3]} * vi2;
      #pragma unroll
      for (int tc = 0; tc < 4; ++tc) {
        f32x2 c101 = {c1[tc][0], c1[tc][1]}, c123 = {c1[tc][2], c1[tc][3]};
        f32x2 c201 = {c2[tc][0], c2[tc][1]}, c223 = {c2[tc][2], c2[tc][3]};
        f32x2 t01 = (c101 * c101) * c201;
        f32x2 t23 = (c123 * c123) * c223;
        qacc2[tc] = __builtin_elementwise_fma(t01, w01, qacc2[tc]);
        qacc2[tc] = __builtin_elementwise_fma(t23, w23, qacc2[tc]);
      }
    }
  }

  // reduce qacc over quads (rows j), publish per-wave partial q.
  // spq overlays sKT rows 0-63: dead for ALL waves during/after the i-loop
  // (only rows 64-79 are read as ext frags), so no barrier needed first.
  #pragma unroll
  for (int tc = 0; tc < 4; ++tc) {
    float s = qacc2[tc][0] + qacc2[tc][1];
    s += __shfl_xor(s, 16, 64);
    s += __shfl_xor(s, 32, 64);
    if (quad == 0) spq[(wv << 6) + tc * 16 + ln15] = s;
  }

  // Hoisted z-independent output half: accv = v @ W3[o8][:64] partial.
  // Overlaps W3 L2 loads with the b2s/Jacobi phases below.
  float accv;
  {
    const float* w3r = &W3[o8 << 7];
    float4 wva = *(const float4*)&w3r[s8 << 3];
    float4 wvb = *(const float4*)&w3r[(s8 << 3) + 4];
    float4 va = *(const float4*)&sv[s8 << 3], vb = *(const float4*)&sv[(s8 << 3) + 4];
    accv = wva.x * va.x + wva.y * va.y + wva.z * va.z + wva.w * va.w
         + wvb.x * vb.x + wvb.y * vb.y + wvb.z * vb.z + wvb.w * vb.w;
  }
  __syncthreads();  // first block-wide sync since setup

  for (int e = t; e < 4096; e += 512)     // g += b2 + b2^T (precomputed, coalesced)
    sg[(e >> 6) * 68 + (e & 63)] += b2s[e];
  __syncthreads();

  if (t < 64) {
    float s = spq[t] + spq[64 + t] + spq[128 + t] + spq[192 + t]
            + spq[256 + t] + spq[320 + t] + spq[384 + t] + spq[448 + t];
    sq[t] = s;
    szz[t] = s / sg[t * 68 + t];   // Jacobi init
  }
  __syncthreads();

  // Jacobi: z' = z + (q - g z)/diag. Single-wave register-matvec:
  // lane r holds g-row r (16 f32x4, loaded once); z in LDS (broadcast).
  // 8 independent 8-deep fma chains; NO per-iter drain (in-wave DS ops
  // execute in order). 10 iters: rho(D^-1 E)~0.27-0.38 => residual
  // 2e-6..6e-5 << bf16-J quantization floor ~1e-3.
  if (t < 64) {
    const float* grow = &sg[t * 68];
    f32x4 gr[16];
    #pragma unroll
    for (int cc = 0; cc < 16; ++cc) gr[cc] = *(const f32x4*)&grow[cc << 2];
    const float dinv = 1.f / grow[t];
    const float qr = sq[t];
    float zr = szz[t];
    #pragma unroll 1
    for (int it = 0; it < 10; ++it) {
      float p[8];
      #pragma unroll
      for (int cc = 0; cc < 8; ++cc) {
        f32x4 za_ = *(const f32x4*)&szz[cc << 3];
        f32x4 zb_ = *(const f32x4*)&szz[(cc << 3) + 4];
        f32x4 ga = gr[cc << 1], gb = gr[(cc << 1) + 1];
        float s = ga[0] * za_[0];
        s = fmaf(ga[1], za_[1], s);
        s = fmaf(ga[2], za_[2], s);
        s = fmaf(ga[3], za_[3], s);
        s = fmaf(gb[0], zb_[0], s);
        s = fmaf(gb[1], zb_[1], s);
        s = fmaf(gb[2], zb_[2], s);
        s = fmaf(gb[3], zb_[3], s);
        p[cc] = s;
      }
      float r4 = ((p[0] + p[1]) + (p[2] + p[3])) + ((p[4] + p[5]) + (p[6] + p[7]));
      zr = zr + (qr - r4) * dinv;
      szz[t] = zr;
      __builtin_amdgcn_sched_barrier(0);
    }
  }
  __syncthreads();

  // out[o] = accv + 0.5 * sum_c z[c] W3[o][64+c]; 8 lanes/row
  {
    const float* w3r = &W3[o8 << 7];
    float4 wda = *(const float4*)&w3r[64 + (s8 << 3)];
    float4 wdb = *(const float4*)&w3r[64 + (s8 << 3) + 4];
    float4 za = *(const float4*)&szz[s8 << 3], zb = *(const float4*)&szz[(s8 << 3) + 4];
    float acc = accv
              + 0.5f * (wda.x * za.x + wda.y * za.y + wda.z * za.z + wda.w * za.w
                      + wdb.x * zb.x + wdb.y * zb.y + wdb.z * zb.z + wdb.w * zb.w);
    acc += __shfl_xor(acc, 1);
    acc += __shfl_xor(acc, 2);
    acc += __shfl_xor(acc, 4);
    if (s8 == 0) out[(n << 6) + o8] = acc;
  }
}

extern "C" void kernel_launch(void* const* d_in, const int* in_sizes, int n_in,
                              void* d_out, int out_size, void* d_ws, size_t ws_size,
                              hipStream_t stream) {
  (void)in_sizes; (void)n_in; (void)out_size; (void)ws_size;
  const float* x  = (const float*)d_in[1];
  const float* v  = (const float*)d_in[2];
  const float* W1 = (const float*)d_in[3];
  const float* b1 = (const float*)d_in[4];
  const float* W2 = (const float*)d_in[5];
  const float* b2 = (const float*)d_in[6];
  const float* W3 = (const float*)d_in[7];
  unsigned short* W2sB = (unsigned short*)d_ws;       // 64*64*64 bf16 = 512 KB
  float* W1T = (float*)((char*)d_ws + (512 << 10));   // 16 KB
  float* b2s = W1T + 4096;                            // 16 KB

  hipLaunchKernelGGL(prep_kernel, dim3(130), dim3(256), 0, stream,
                     W2, W1, b2, W2sB, W1T, b2s);
  hipLaunchKernelGGL(conn_kernel, dim3(256), dim3(512), 0, stream,
                     x, v, W1, b1, W3, W2sB, W1T, b2s, (float*)d_out);
}

// Round 13
// 92.602 us; speedup vs baseline: 2.2568x; 1.0053x over previous
//
#include <hip/hip_runtime.h>
#include <math.h>
#include <stdint.h>

// n=256 samples, d=64, fp32 in/out. J-path bf16 MFMA.
//   K[m][l] = (1-h^2)[m] W1[m][l];  sKT[l][m] = K[m][l] (bf16), row 64 = h
//   W2sB[i][j][m] = bf16(W2[(i,j)][m] + W2[(j,i)][m])  (symmetric in i,j)
//   slab-frag af[t] and sKT-frag bf[t] are BOTH valid as A or B:
//     C1 = mfma(A=af[tr], B=bf[tc]) -> Ji[j][l];  C2 = mfma(A=bf[tr], B=af[tc])
//     -> Ji[l][j] at the SAME (lane,reg) => q in-register, no LDS transpose.
// Ledger: 512thr/128-VGPR diet (v7) 2 waves/SIMD spill-free; MFMA batching
//   (v9) -2.9us; pk-consume + 1-wave Jacobi (v10) -2.9us; W1T/b2s + 8x8
//   Jacobi chains (v11) -2.3us; v12 (drop DMA + Jacobi10 + hoist + fast
//   tanh) NET ZERO -> hypothesis: (b,c,d) gained ~1.5us, (a) lost ~1.5us.
//   v8's "DMA neutral" was measured in the v7 FUSED structure (load
//   latency hidden behind serialized MFMA chains); v9's batched structure
//   drains MFMAs fast, re-exposing the 8 direct L2 loads per ii.
// v13: single-variable A/B vs v12 — restore the DMA slab double-buffer
//   (stage_slab prefetch one slab ahead, coalesced 1KB/instr, LDS frag
//   reads ~120cy, swizzled) while keeping v12's (b) Jacobi 10 iters,
//   (c) hoisted accv, (d) exp2f tanh.

typedef short short8 __attribute__((ext_vector_type(8)));
typedef float f32x4 __attribute__((ext_vector_type(4)));
typedef float f32x2 __attribute__((ext_vector_type(2)));

__device__ __forceinline__ unsigned short f2bf(float f) {
  unsigned int u = __builtin_bit_cast(unsigned int, f);
  u += 0x7fffu + ((u >> 16) & 1u);
  return (unsigned short)(u >> 16);
}

__device__ __forceinline__ short8 as_short8(uint4 u) {
  union { uint4 a; short8 b; } cv; cv.a = u; return cv.b;
}

// DMA one 8KB slab (64 rows x 128B) global->LDS, 16B/lane/instr, 8 instrs.
// Source pre-swizzled so lds[row j][16B-slot s] = global(j, s ^ (j&7)).
__device__ __forceinline__ void stage_slab(const unsigned short* gslab,
                                           unsigned short* lbase, int lane) {
  const int srcoff = ((lane >> 3) << 6) + (((lane & 7) ^ (lane >> 3)) << 3);  // shorts
  const unsigned short* gsrc = gslab + srcoff;
  #pragma unroll
  for (int k = 0; k < 8; ++k) {
    __builtin_amdgcn_global_load_lds(
        (const __attribute__((address_space(1))) unsigned int*)(gsrc + (k << 9)),
        (__attribute__((address_space(3))) unsigned int*)(lbase + (k << 9)),
        16, 0, 0);
  }
}

// Blocks 0-127: W2sB (bf16 symmetrized W2 slabs). Block 128: W1T (f32).
// Block 129: b2s = b2 + b2^T (f32). All sample-invariant.
__global__ __launch_bounds__(256) void prep_kernel(
    const float* __restrict__ W2, const float* __restrict__ W1,
    const float* __restrict__ b2, unsigned short* __restrict__ W2sB,
    float* __restrict__ W1T, float* __restrict__ b2s) {
  const int b = blockIdx.x;
  if (b < 128) {
    int g = b * 256 + threadIdx.x;      // each thread: 8 consecutive m
    int i = g >> 9, j = (g >> 3) & 63, m8 = (g & 7) << 3;
    const float* pa = &W2[((((i << 6) + j) << 6) + m8)];
    const float* pb = &W2[((((j << 6) + i) << 6) + m8)];
    float4 a0 = *(const float4*)pa, a1 = *(const float4*)(pa + 4);
    float4 b0 = *(const float4*)pb, b1 = *(const float4*)(pb + 4);
    short8 r;
    r[0] = (short)f2bf(a0.x + b0.x); r[1] = (short)f2bf(a0.y + b0.y);
    r[2] = (short)f2bf(a0.z + b0.z); r[3] = (short)f2bf(a0.w + b0.w);
    r[4] = (short)f2bf(a1.x + b1.x); r[5] = (short)f2bf(a1.y + b1.y);
    r[6] = (short)f2bf(a1.z + b1.z); r[7] = (short)f2bf(a1.w + b1.w);
    *(short8*)&W2sB[(size_t)g << 3] = r;
  } else if (b == 128) {
    for (int e = threadIdx.x; e < 4096; e += 256) {
      int l = e >> 6, m = e & 63;
      W1T[e] = W1[(m << 6) + l];              // W1T[l][m] = W1[m][l]
    }
  } else {
    for (int e = threadIdx.x; e < 4096; e += 256) {
      int r = e >> 6, c = e & 63;
      b2s[e] = b2[(r << 6) + c] + b2[(c << 6) + r];
    }
  }
}

__global__ __launch_bounds__(512) void conn_kernel(
    const float* __restrict__ x, const float* __restrict__ v,
    const float* __restrict__ W1, const float* __restrict__ b1,
    const float* __restrict__ W3, const unsigned short* __restrict__ W2sB,
    const float* __restrict__ W1T, const float* __restrict__ b2s,
    float* __restrict__ out) {
  __shared__ __align__(16) unsigned short sAF[8][2][4096];  // per-wave slab dbuf, 128KB
  __shared__ __align__(16) unsigned short sKT[80 * 80];  // rows 0-63 = K^T, 64 = h, 65-79 = 0
  __shared__ __align__(16) float sg[64 * 68];            // g, stride 68 (f32x4-aligned stores)
  __shared__ __align__(16) float sh[64], sv[64], sx[64];

  // Overlays into sKT rows 0-63 (bytes 0..10239): dead once bf frags are
  // pinned; ext reads use only rows 64-79 (bytes >= 10240).
  float* const spq = (float*)sKT;          // [8][64] = 2048B
  float* const sq  = (float*)sKT + 512;    // 256B
  float* const szz = (float*)sKT + 576;    // [64] = 256B (z vector)

  const int n = blockIdx.x, t = threadIdx.x;
  const int wv = t >> 6, lane = t & 63, ln15 = lane & 15, quad = lane >> 4;
  const int o8 = t >> 3, s8 = t & 7;

  if (t < 64) sx[t] = x[(n << 6) + t];
  else if (t < 128) sv[t - 64] = v[(n << 6) + (t - 64)];
  for (int e = t; e < 1280; e += 512) sKT[5120 + e] = 0;  // zero rows 64..79
  __syncthreads();

  // h[o] = tanh(b1[o] + sum_l sx[l] W1[o][l]); 8 lanes per output, shfl reduce
  {
    const float* w1r = &W1[(o8 << 6) + (s8 << 3)];
    float4 wa = *(const float4*)w1r, wb = *(const float4*)(w1r + 4);
    float4 xa = *(const float4*)&sx[s8 << 3], xb = *(const float4*)&sx[(s8 << 3) + 4];
    float acc = wa.x * xa.x + wa.y * xa.y + wa.z * xa.z + wa.w * xa.w
              + wb.x * xb.x + wb.y * xb.y + wb.z * xb.z + wb.w * xb.w;
    acc += __shfl_xor(acc, 1);
    acc += __shfl_xor(acc, 2);
    acc += __shfl_xor(acc, 4);
    if (s8 == 0) {
      float a = acc + b1[o8];
      a = fminf(10.f, fmaxf(-10.f, a));          // tanh(10)=1-4e-9, safe clamp
      float e2 = exp2f(a * 2.8853900817779268f); // e^(2a) via hw v_exp_f32
      sh[o8] = (e2 - 1.f) / (e2 + 1.f);
    }
  }
  __syncthreads();

  for (int e = t; e < 4096; e += 512) {   // coalesced: W1T[l*64+m]
    int m = e & 63, l = e >> 6;
    float hm = sh[m];
    sKT[l * 80 + m] = f2bf((1.f - hm * hm) * W1T[e]);
  }
  if (t < 64) sKT[64 * 80 + t] = f2bf(sh[t]);
  __syncthreads();

  // sKT frags: tiles 0..3 dual-use (A for C2 row-tile / B for C1 col-tile).
  // Tile 4 (ext: h row) is reloaded from LDS per use (VGPR diet).
  short8 bf[4][2];
  #pragma unroll
  for (int tc = 0; tc < 4; ++tc)
    #pragma unroll
    for (int ks = 0; ks < 2; ++ks)
      bf[tc][ks] = *(const short8*)&sKT[(tc * 16 + ln15) * 80 + ks * 32 + quad * 8];

  f32x2 qacc2[4] = {{0.f, 0.f}, {0.f, 0.f}, {0.f, 0.f}, {0.f, 0.f}};

  // Wave wv owns i in [8*wv, 8*wv+8). Slab frags from LDS, swizzled reads:
  // element slot' = slot ^ (ln15&7); af[tc][1] address = [0] address ^ 32.
  const int f0 = (ln15 << 6) + (((quad ^ ln15) & 7) << 3);
  const int extoff = (64 + ln15) * 80 + quad * 8;   // h-row frag base (+32 for ks=1)
  unsigned short* const myAF = &sAF[wv][0][0];
  const unsigned short* const gbase = W2sB + ((size_t)(8 * wv) << 12);

  stage_slab(gbase, myAF, lane);   // prologue: slab 0 -> buf 0

  #pragma unroll 1
  for (int ii = 0; ii < 8; ++ii) {
    asm volatile("s_waitcnt vmcnt(0)" ::: "memory");   // buf[ii&1] DMA complete
    __builtin_amdgcn_sched_barrier(0);
    if (ii < 7)  // prefetch next slab into the other buffer; flies across compute
      stage_slab(gbase + ((size_t)(ii + 1) << 12), myAF + (((ii & 1) ^ 1) << 12), lane);

    const unsigned short* buf = myAF + ((ii & 1) << 12);
    uint4 af[4][2];
    #pragma unroll
    for (int tc = 0; tc < 4; ++tc) {
      af[tc][0] = *(const uint4*)&buf[(tc << 10) + f0];
      af[tc][1] = *(const uint4*)&buf[(tc << 10) + (f0 ^ 32)];
    }
    const int i = 8 * wv + ii;
    const float vi = sv[i];

    #pragma unroll
    for (int tr = 0; tr < 4; ++tr) {
      short8 a0 = as_short8(af[tr][0]), a1 = as_short8(af[tr][1]);
      // Batch all 8 independent 2-deep MFMA chains before any VALU consume:
      // cross-tc ILP hides MFMA latency.
      f32x4 c1[4], c2[4];
      #pragma unroll
      for (int tc = 0; tc < 4; ++tc) {
        f32x4 z4 = {0.f, 0.f, 0.f, 0.f};
        f32x4 u = __builtin_amdgcn_mfma_f32_16x16x32_bf16(a0, bf[tc][0], z4, 0, 0, 0);
        c1[tc]  = __builtin_amdgcn_mfma_f32_16x16x32_bf16(a1, bf[tc][1], u, 0, 0, 0);
        f32x4 w = __builtin_amdgcn_mfma_f32_16x16x32_bf16(bf[tr][0], as_short8(af[tc][0]), z4, 0, 0, 0);
        c2[tc]  = __builtin_amdgcn_mfma_f32_16x16x32_bf16(bf[tr][1], as_short8(af[tc][1]), w, 0, 0, 0);
      }
      {
        short8 e0 = *(const short8*)&sKT[extoff];
        short8 e1 = *(const short8*)&sKT[extoff + 32];
        f32x4 z4 = {0.f, 0.f, 0.f, 0.f};
        f32x4 u  = __builtin_amdgcn_mfma_f32_16x16x32_bf16(a0, e0, z4, 0, 0, 0);
        f32x4 ce = __builtin_amdgcn_mfma_f32_16x16x32_bf16(a1, e1, u, 0, 0, 0);
        if (ln15 == 0)  // g[i][j], j = 16*tr + 4*quad + r
          *(f32x4*)&sg[i * 68 + tr * 16 + quad * 4] = ce;
      }
      // Packed-fp32 consume: per tc 6 pk ops, fma folded into qacc2.
      f32x4 svj = *(const f32x4*)&sv[tr * 16 + quad * 4];
      f32x2 vi2 = {vi, vi};
      f32x2 w01 = f32x2{svj[0], svj[1]} * vi2;
      f32x2 w23 = f32x2{svj[2], svj[3]} * vi2;
      #pragma unroll
      for (int tc = 0; tc < 4; ++tc) {
        f32x2 c101 = {c1[tc][0], c1[tc][1]}, c123 = {c1[tc][2], c1[tc][3]};
        f32x2 c201 = {c2[tc][0], c2[tc][1]}, c223 = {c2[tc][2], c2[tc][3]};
        f32x2 t01 = (c101 * c101) * c201;
        f32x2 t23 = (c123 * c123) * c223;
        qacc2[tc] = __builtin_elementwise_fma(t01, w01, qacc2[tc]);
        qacc2[tc] = __builtin_elementwise_fma(t23, w23, qacc2[tc]);
      }
    }
  }

  // reduce qacc over quads (rows j), publish per-wave partial q.
  // spq overlays sKT rows 0-63: dead for ALL waves during/after the i-loop
  // (only rows 64-79 are read as ext frags), so no barrier needed first.
  #pragma unroll
  for (int tc = 0; tc < 4; ++tc) {
    float s = qacc2[tc][0] + qacc2[tc][1];
    s += __shfl_xor(s, 16, 64);
    s += __shfl_xor(s, 32, 64);
    if (quad == 0) spq[(wv << 6) + tc * 16 + ln15] = s;
  }

  // Hoisted z-independent output half: accv = v @ W3[o8][:64] partial.
  // Overlaps W3 L2 loads with the b2s/Jacobi phases below.
  float accv;
  {
    const float* w3r = &W3[o8 << 7];
    float4 wva = *(const float4*)&w3r[s8 << 3];
    float4 wvb = *(const float4*)&w3r[(s8 << 3) + 4];
    float4 va = *(const float4*)&sv[s8 << 3], vb = *(const float4*)&sv[(s8 << 3) + 4];
    accv = wva.x * va.x + wva.y * va.y + wva.z * va.z + wva.w * va.w
         + wvb.x * vb.x + wvb.y * vb.y + wvb.z * vb.z + wvb.w * vb.w;
  }
  __syncthreads();  // first block-wide sync since setup

  for (int e = t; e < 4096; e += 512)     // g += b2 + b2^T (precomputed, coalesced)
    sg[(e >> 6) * 68 + (e & 63)] += b2s[e];
  __syncthreads();

  if (t < 64) {
    float s = spq[t] + spq[64 + t] + spq[128 + t] + spq[192 + t]
            + spq[256 + t] + spq[320 + t] + spq[384 + t] + spq[448 + t];
    sq[t] = s;
    szz[t] = s / sg[t * 68 + t];   // Jacobi init
  }
  __syncthreads();

  // Jacobi: z' = z + (q - g z)/diag. Single-wave register-matvec:
  // lane r holds g-row r (16 f32x4, loaded once); z in LDS (broadcast).
  // 8 independent 8-deep fma chains; NO per-iter drain (in-wave DS ops
  // execute in order). 10 iters: rho(D^-1 E)~0.27-0.38 => residual
  // 2e-6..6e-5 << bf16-J quantization floor ~1e-3.
  if (t < 64) {
    const float* grow = &sg[t * 68];
    f32x4 gr[16];
    #pragma unroll
    for (int cc = 0; cc < 16; ++cc) gr[cc] = *(const f32x4*)&grow[cc << 2];
    const float dinv = 1.f / grow[t];
    const float qr = sq[t];
    float zr = szz[t];
    #pragma unroll 1
    for (int it = 0; it < 10; ++it) {
      float p[8];
      #pragma unroll
      for (int cc = 0; cc < 8; ++cc) {
        f32x4 za_ = *(const f32x4*)&szz[cc << 3];
        f32x4 zb_ = *(const f32x4*)&szz[(cc << 3) + 4];
        f32x4 ga = gr[cc << 1], gb = gr[(cc << 1) + 1];
        float s = ga[0] * za_[0];
        s = fmaf(ga[1], za_[1], s);
        s = fmaf(ga[2], za_[2], s);
        s = fmaf(ga[3], za_[3], s);
        s = fmaf(gb[0], zb_[0], s);
        s = fmaf(gb[1], zb_[1], s);
        s = fmaf(gb[2], zb_[2], s);
        s = fmaf(gb[3], zb_[3], s);
        p[cc] = s;
      }
      float r4 = ((p[0] + p[1]) + (p[2] + p[3])) + ((p[4] + p[5]) + (p[6] + p[7]));
      zr = zr + (qr - r4) * dinv;
      szz[t] = zr;
      __builtin_amdgcn_sched_barrier(0);
    }
  }
  __syncthreads();

  // out[o] = accv + 0.5 * sum_c z[c] W3[o][64+c]; 8 lanes/row
  {
    const float* w3r = &W3[o8 << 7];
    float4 wda = *(const float4*)&w3r[64 + (s8 << 3)];
    float4 wdb = *(const float4*)&w3r[64 + (s8 << 3) + 4];
    float4 za = *(const float4*)&szz[s8 << 3], zb = *(const float4*)&szz[(s8 << 3) + 4];
    float acc = accv
              + 0.5f * (wda.x * za.x + wda.y * za.y + wda.z * za.z + wda.w * za.w
                      + wdb.x * zb.x + wdb.y * zb.y + wdb.z * zb.z + wdb.w * zb.w);
    acc += __shfl_xor(acc, 1);
    acc += __shfl_xor(acc, 2);
    acc += __shfl_xor(acc, 4);
    if (s8 == 0) out[(n << 6) + o8] = acc;
  }
}

extern "C" void kernel_launch(void* const* d_in, const int* in_sizes, int n_in,
                              void* d_out, int out_size, void* d_ws, size_t ws_size,
                              hipStream_t stream) {
  (void)in_sizes; (void)n_in; (void)out_size; (void)ws_size;
  const float* x  = (const float*)d_in[1];
  const float* v  = (const float*)d_in[2];
  const float* W1 = (const float*)d_in[3];
  const float* b1 = (const float*)d_in[4];
  const float* W2 = (const float*)d_in[5];
  const float* b2 = (const float*)d_in[6];
  const float* W3 = (const float*)d_in[7];
  unsigned short* W2sB = (unsigned short*)d_ws;       // 64*64*64 bf16 = 512 KB
  float* W1T = (float*)((char*)d_ws + (512 << 10));   // 16 KB
  float* b2s = W1T + 4096;                            // 16 KB

  hipLaunchKernelGGL(prep_kernel, dim3(130), dim3(256), 0, stream,
                     W2, W1, b2, W2sB, W1T, b2s);
  hipLaunchKernelGGL(conn_kernel, dim3(256), dim3(512), 0, stream,
                     x, v, W1, b1, W3, W2sB, W1T, b2s, (float*)d_out);
}

// Round 14
// 91.811 us; speedup vs baseline: 2.2762x; 1.0086x over previous
//
#include <hip/hip_runtime.h>
#include <math.h>
#include <stdint.h>

// n=256 samples, d=64, fp32 in/out. J-path bf16 MFMA.
//   K[m][l] = (1-h^2)[m] W1[m][l];  sKT[l][m] = K[m][l] (bf16), row 64 = h
//   W2sB[i][j][m] = bf16(W2[(i,j)][m] + W2[(j,i)][m])  (symmetric in i,j)
//   slab-frag af[t] and sKT-frag bf[t] are BOTH valid as A or B:
//     C1 = mfma(A=af[tr], B=bf[tc]) -> Ji[j][l];  C2 = mfma(A=bf[tr], B=af[tc])
//     -> Ji[l][j] at the SAME (lane,reg) => q in-register, no LDS transpose.
// Ledger: v7 512thr/128-VGPR spill-free (2 w/SIMD); v9 MFMA batching -2.9;
//   v10 pk-consume + 1-wave Jacobi -2.9; v11 W1T/b2s + 8x8 chains -2.3;
//   v12 net-zero (DMA drop lost what b/c/d gained); v13 DMA restored -0.5.
//   Effective clock ~810MHz (bursty) => serial-phase latency is the lever.
// v14: compress prologue+tail serial chains without touching the i-loop:
//   (a) early-issue W1-row + W1T-chunk loads at kernel entry (overlap the
//       x/v latency hop; barriers drain vmcnt anyway); sKT build becomes
//       2xfloat4 + 1 b128 store per thread;
//   (b) delete the b2s block-pass + 2 barriers: Jacobi lane t loads its
//       b2s row (16 f32x4) BEFORE the barrier (latency hides under arrival
//       +drain) and adds the LDS sg row after; diag via 2 scalar reads
//       (no runtime vector indexing); q-init merged into the same region;
//   (c) hoist W3[:,64:] loads above the Jacobi barrier (8 regs across).

typedef short short8 __attribute__((ext_vector_type(8)));
typedef float f32x4 __attribute__((ext_vector_type(4)));
typedef float f32x2 __attribute__((ext_vector_type(2)));

__device__ __forceinline__ unsigned short f2bf(float f) {
  unsigned int u = __builtin_bit_cast(unsigned int, f);
  u += 0x7fffu + ((u >> 16) & 1u);
  return (unsigned short)(u >> 16);
}

__device__ __forceinline__ short8 as_short8(uint4 u) {
  union { uint4 a; short8 b; } cv; cv.a = u; return cv.b;
}

// DMA one 8KB slab (64 rows x 128B) global->LDS, 16B/lane/instr, 8 instrs.
// Source pre-swizzled so lds[row j][16B-slot s] = global(j, s ^ (j&7)).
__device__ __forceinline__ void stage_slab(const unsigned short* gslab,
                                           unsigned short* lbase, int lane) {
  const int srcoff = ((lane >> 3) << 6) + (((lane & 7) ^ (lane >> 3)) << 3);  // shorts
  const unsigned short* gsrc = gslab + srcoff;
  #pragma unroll
  for (int k = 0; k < 8; ++k) {
    __builtin_amdgcn_global_load_lds(
        (const __attribute__((address_space(1))) unsigned int*)(gsrc + (k << 9)),
        (__attribute__((address_space(3))) unsigned int*)(lbase + (k << 9)),
        16, 0, 0);
  }
}

// Blocks 0-127: W2sB (bf16 symmetrized W2 slabs). Block 128: W1T (f32).
// Block 129: b2s = b2 + b2^T (f32). All sample-invariant.
__global__ __launch_bounds__(256) void prep_kernel(
    const float* __restrict__ W2, const float* __restrict__ W1,
    const float* __restrict__ b2, unsigned short* __restrict__ W2sB,
    float* __restrict__ W1T, float* __restrict__ b2s) {
  const int b = blockIdx.x;
  if (b < 128) {
    int g = b * 256 + threadIdx.x;      // each thread: 8 consecutive m
    int i = g >> 9, j = (g >> 3) & 63, m8 = (g & 7) << 3;
    const float* pa = &W2[((((i << 6) + j) << 6) + m8)];
    const float* pb = &W2[((((j << 6) + i) << 6) + m8)];
    float4 a0 = *(const float4*)pa, a1 = *(const float4*)(pa + 4);
    float4 b0 = *(const float4*)pb, b1 = *(const float4*)(pb + 4);
    short8 r;
    r[0] = (short)f2bf(a0.x + b0.x); r[1] = (short)f2bf(a0.y + b0.y);
    r[2] = (short)f2bf(a0.z + b0.z); r[3] = (short)f2bf(a0.w + b0.w);
    r[4] = (short)f2bf(a1.x + b1.x); r[5] = (short)f2bf(a1.y + b1.y);
    r[6] = (short)f2bf(a1.z + b1.z); r[7] = (short)f2bf(a1.w + b1.w);
    *(short8*)&W2sB[(size_t)g << 3] = r;
  } else if (b == 128) {
    for (int e = threadIdx.x; e < 4096; e += 256) {
      int l = e >> 6, m = e & 63;
      W1T[e] = W1[(m << 6) + l];              // W1T[l][m] = W1[m][l]
    }
  } else {
    for (int e = threadIdx.x; e < 4096; e += 256) {
      int r = e >> 6, c = e & 63;
      b2s[e] = b2[(r << 6) + c] + b2[(c << 6) + r];
    }
  }
}

__global__ __launch_bounds__(512) void conn_kernel(
    const float* __restrict__ x, const float* __restrict__ v,
    const float* __restrict__ W1, const float* __restrict__ b1,
    const float* __restrict__ W3, const unsigned short* __restrict__ W2sB,
    const float* __restrict__ W1T, const float* __restrict__ b2s,
    float* __restrict__ out) {
  __shared__ __align__(16) unsigned short sAF[8][2][4096];  // per-wave slab dbuf, 128KB
  __shared__ __align__(16) unsigned short sKT[80 * 80];  // rows 0-63 = K^T, 64 = h, 65-79 = 0
  __shared__ __align__(16) float sg[64 * 68];            // g, stride 68 (f32x4-aligned stores)
  __shared__ __align__(16) float sh[64], sv[64], sx[64];

  // Overlays into sKT rows 0-63 (bytes 0..10239): dead once bf frags are
  // pinned; ext reads use only rows 64-79 (bytes >= 10240).
  float* const spq = (float*)sKT;          // [8][64] = 2048B
  float* const szz = (float*)sKT + 576;    // [64] = 256B (z vector)

  const int n = blockIdx.x, t = threadIdx.x;
  const int wv = t >> 6, lane = t & 63, ln15 = lane & 15, quad = lane >> 4;
  const int o8 = t >> 3, s8 = t & 7;

  // ---- Early-issue all sample-invariant loads (complete by barrier 1's
  // vmcnt drain; latency overlaps the x/v hop). Regs die before i-loop.
  const float* w1r = &W1[(o8 << 6) + (s8 << 3)];
  float4 wa = *(const float4*)w1r, wb = *(const float4*)(w1r + 4);
  const int lL = t >> 3, m0 = (t & 7) << 3;          // sKT build: row lL, cols m0..m0+7
  float4 wt0 = *(const float4*)&W1T[(lL << 6) + m0];
  float4 wt1 = *(const float4*)&W1T[(lL << 6) + m0 + 4];

  if (t < 64) sx[t] = x[(n << 6) + t];
  else if (t < 128) sv[t - 64] = v[(n << 6) + (t - 64)];
  for (int e = t; e < 1280; e += 512) sKT[5120 + e] = 0;  // zero rows 64..79
  __syncthreads();

  // h[o] = tanh(b1[o] + sum_l sx[l] W1[o][l]); 8 lanes per output, shfl reduce
  {
    float4 xa = *(const float4*)&sx[s8 << 3], xb = *(const float4*)&sx[(s8 << 3) + 4];
    float acc = wa.x * xa.x + wa.y * xa.y + wa.z * xa.z + wa.w * xa.w
              + wb.x * xb.x + wb.y * xb.y + wb.z * xb.z + wb.w * xb.w;
    acc += __shfl_xor(acc, 1);
    acc += __shfl_xor(acc, 2);
    acc += __shfl_xor(acc, 4);
    if (s8 == 0) {
      float a = acc + b1[o8];
      a = fminf(10.f, fmaxf(-10.f, a));          // tanh(10)=1-4e-9, safe clamp
      float e2 = exp2f(a * 2.8853900817779268f); // e^(2a) via hw v_exp_f32
      sh[o8] = (e2 - 1.f) / (e2 + 1.f);
    }
  }
  __syncthreads();

  // sKT build: thread -> row lL, cols m0..m0+7; W1T chunk preloaded.
  {
    float4 h0 = *(const float4*)&sh[m0], h1 = *(const float4*)&sh[m0 + 4];
    short8 kk;
    kk[0] = (short)f2bf((1.f - h0.x * h0.x) * wt0.x);
    kk[1] = (short)f2bf((1.f - h0.y * h0.y) * wt0.y);
    kk[2] = (short)f2bf((1.f - h0.z * h0.z) * wt0.z);
    kk[3] = (short)f2bf((1.f - h0.w * h0.w) * wt0.w);
    kk[4] = (short)f2bf((1.f - h1.x * h1.x) * wt1.x);
    kk[5] = (short)f2bf((1.f - h1.y * h1.y) * wt1.y);
    kk[6] = (short)f2bf((1.f - h1.z * h1.z) * wt1.z);
    kk[7] = (short)f2bf((1.f - h1.w * h1.w) * wt1.w);
    *(short8*)&sKT[lL * 80 + m0] = kk;
  }
  if (t < 64) sKT[64 * 80 + t] = f2bf(sh[t]);
  __syncthreads();

  // sKT frags: tiles 0..3 dual-use (A for C2 row-tile / B for C1 col-tile).
  // Tile 4 (ext: h row) is reloaded from LDS per use (VGPR diet).
  short8 bf[4][2];
  #pragma unroll
  for (int tc = 0; tc < 4; ++tc)
    #pragma unroll
    for (int ks = 0; ks < 2; ++ks)
      bf[tc][ks] = *(const short8*)&sKT[(tc * 16 + ln15) * 80 + ks * 32 + quad * 8];

  f32x2 qacc2[4] = {{0.f, 0.f}, {0.f, 0.f}, {0.f, 0.f}, {0.f, 0.f}};

  // Wave wv owns i in [8*wv, 8*wv+8). Slab frags from LDS, swizzled reads:
  // element slot' = slot ^ (ln15&7); af[tc][1] address = [0] address ^ 32.
  const int f0 = (ln15 << 6) + (((quad ^ ln15) & 7) << 3);
  const int extoff = (64 + ln15) * 80 + quad * 8;   // h-row frag base (+32 for ks=1)
  unsigned short* const myAF = &sAF[wv][0][0];
  const unsigned short* const gbase = W2sB + ((size_t)(8 * wv) << 12);

  stage_slab(gbase, myAF, lane);   // prologue: slab 0 -> buf 0

  #pragma unroll 1
  for (int ii = 0; ii < 8; ++ii) {
    asm volatile("s_waitcnt vmcnt(0)" ::: "memory");   // buf[ii&1] DMA complete
    __builtin_amdgcn_sched_barrier(0);
    if (ii < 7)  // prefetch next slab into the other buffer; flies across compute
      stage_slab(gbase + ((size_t)(ii + 1) << 12), myAF + (((ii & 1) ^ 1) << 12), lane);

    const unsigned short* buf = myAF + ((ii & 1) << 12);
    uint4 af[4][2];
    #pragma unroll
    for (int tc = 0; tc < 4; ++tc) {
      af[tc][0] = *(const uint4*)&buf[(tc << 10) + f0];
      af[tc][1] = *(const uint4*)&buf[(tc << 10) + (f0 ^ 32)];
    }
    const int i = 8 * wv + ii;
    const float vi = sv[i];

    #pragma unroll
    for (int tr = 0; tr < 4; ++tr) {
      short8 a0 = as_short8(af[tr][0]), a1 = as_short8(af[tr][1]);
      // Batch all 8 independent 2-deep MFMA chains before any VALU consume:
      // cross-tc ILP hides MFMA latency.
      f32x4 c1[4], c2[4];
      #pragma unroll
      for (int tc = 0; tc < 4; ++tc) {
        f32x4 z4 = {0.f, 0.f, 0.f, 0.f};
        f32x4 u = __builtin_amdgcn_mfma_f32_16x16x32_bf16(a0, bf[tc][0], z4, 0, 0, 0);
        c1[tc]  = __builtin_amdgcn_mfma_f32_16x16x32_bf16(a1, bf[tc][1], u, 0, 0, 0);
        f32x4 w = __builtin_amdgcn_mfma_f32_16x16x32_bf16(bf[tr][0], as_short8(af[tc][0]), z4, 0, 0, 0);
        c2[tc]  = __builtin_amdgcn_mfma_f32_16x16x32_bf16(bf[tr][1], as_short8(af[tc][1]), w, 0, 0, 0);
      }
      {
        short8 e0 = *(const short8*)&sKT[extoff];
        short8 e1 = *(const short8*)&sKT[extoff + 32];
        f32x4 z4 = {0.f, 0.f, 0.f, 0.f};
        f32x4 u  = __builtin_amdgcn_mfma_f32_16x16x32_bf16(a0, e0, z4, 0, 0, 0);
        f32x4 ce = __builtin_amdgcn_mfma_f32_16x16x32_bf16(a1, e1, u, 0, 0, 0);
        if (ln15 == 0)  // g[i][j], j = 16*tr + 4*quad + r
          *(f32x4*)&sg[i * 68 + tr * 16 + quad * 4] = ce;
      }
      // Packed-fp32 consume: per tc 6 pk ops, fma folded into qacc2.
      f32x4 svj = *(const f32x4*)&sv[tr * 16 + quad * 4];
      f32x2 vi2 = {vi, vi};
      f32x2 w01 = f32x2{svj[0], svj[1]} * vi2;
      f32x2 w23 = f32x2{svj[2], svj[3]} * vi2;
      #pragma unroll
      for (int tc = 0; tc < 4; ++tc) {
        f32x2 c101 = {c1[tc][0], c1[tc][1]}, c123 = {c1[tc][2], c1[tc][3]};
        f32x2 c201 = {c2[tc][0], c2[tc][1]}, c223 = {c2[tc][2], c2[tc][3]};
        f32x2 t01 = (c101 * c101) * c201;
        f32x2 t23 = (c123 * c123) * c223;
        qacc2[tc] = __builtin_elementwise_fma(t01, w01, qacc2[tc]);
        qacc2[tc] = __builtin_elementwise_fma(t23, w23, qacc2[tc]);
      }
    }
  }

  // reduce qacc over quads (rows j), publish per-wave partial q.
  // spq overlays sKT rows 0-63: dead for ALL waves during/after the i-loop
  // (only rows 64-79 are read as ext frags), so no barrier needed first.
  #pragma unroll
  for (int tc = 0; tc < 4; ++tc) {
    float s = qacc2[tc][0] + qacc2[tc][1];
    s += __shfl_xor(s, 16, 64);
    s += __shfl_xor(s, 32, 64);
    if (quad == 0) spq[(wv << 6) + tc * 16 + ln15] = s;
  }

  // Hoisted output operands: accv = v @ W3[o8][:64]; wda/wdb = W3[o8][64:]
  // held across Jacobi (i-loop regs dead). Overlaps W3 L2 latency.
  float accv;
  float4 wda, wdb;
  {
    const float* w3r = &W3[o8 << 7];
    float4 wva = *(const float4*)&w3r[s8 << 3];
    float4 wvb = *(const float4*)&w3r[(s8 << 3) + 4];
    wda = *(const float4*)&w3r[64 + (s8 << 3)];
    wdb = *(const float4*)&w3r[64 + (s8 << 3) + 4];
    float4 va = *(const float4*)&sv[s8 << 3], vb = *(const float4*)&sv[(s8 << 3) + 4];
    accv = wva.x * va.x + wva.y * va.y + wva.z * va.z + wva.w * va.w
         + wvb.x * vb.x + wvb.y * vb.y + wvb.z * vb.z + wvb.w * vb.w;
  }

  // Jacobi wave pre-loads its b2s row BEFORE the barrier: the 16 f32x4
  // global loads complete during barrier arrival + vmcnt drain.
  f32x4 gr[16];
  float b2diag = 0.f;
  if (t < 64) {
    const float* b2row = &b2s[t << 6];
    #pragma unroll
    for (int cc = 0; cc < 16; ++cc) gr[cc] = *(const f32x4*)&b2row[cc << 2];
    b2diag = b2row[t];
  }
  __syncthreads();  // first block-wide sync since setup; sg/spq now visible

  // Jacobi: z' = z + (q - g z)/diag, g = sg + b2s (b2s folded into gr).
  // Single-wave register-matvec: lane r holds g-row r; z in LDS broadcast.
  // 8 independent 8-deep fma chains; NO per-iter drain (in-wave DS is
  // in-order). 10 iters: rho(D^-1 E)~0.27-0.38 => residual 2e-6..6e-5
  // << bf16-J quantization floor ~1e-3.
  if (t < 64) {
    const float* grow = &sg[t * 68];
    #pragma unroll
    for (int cc = 0; cc < 16; ++cc) {
      f32x4 s4 = *(const f32x4*)&grow[cc << 2];
      gr[cc] += s4;
    }
    float q = spq[t] + spq[64 + t] + spq[128 + t] + spq[192 + t]
            + spq[256 + t] + spq[320 + t] + spq[384 + t] + spq[448 + t];
    const float dinv = 1.f / (grow[t] + b2diag);
    float zr = q * dinv;
    szz[t] = zr;
    #pragma unroll 1
    for (int it = 0; it < 10; ++it) {
      float p[8];
      #pragma unroll
      for (int cc = 0; cc < 8; ++cc) {
        f32x4 za_ = *(const f32x4*)&szz[cc << 3];
        f32x4 zb_ = *(const f32x4*)&szz[(cc << 3) + 4];
        f32x4 ga = gr[cc << 1], gb = gr[(cc << 1) + 1];
        float s = ga[0] * za_[0];
        s = fmaf(ga[1], za_[1], s);
        s = fmaf(ga[2], za_[2], s);
        s = fmaf(ga[3], za_[3], s);
        s = fmaf(gb[0], zb_[0], s);
        s = fmaf(gb[1], zb_[1], s);
        s = fmaf(gb[2], zb_[2], s);
        s = fmaf(gb[3], zb_[3], s);
        p[cc] = s;
      }
      float r4 = ((p[0] + p[1]) + (p[2] + p[3])) + ((p[4] + p[5]) + (p[6] + p[7]));
      zr = zr + (q - r4) * dinv;
      szz[t] = zr;
      __builtin_amdgcn_sched_barrier(0);
    }
  }
  __syncthreads();

  // out[o] = accv + 0.5 * sum_c z[c] W3[o][64+c]; 8 lanes/row
  {
    float4 za = *(const float4*)&szz[s8 << 3], zb = *(const float4*)&szz[(s8 << 3) + 4];
    float acc = accv
              + 0.5f * (wda.x * za.x + wda.y * za.y + wda.z * za.z + wda.w * za.w
                      + wdb.x * zb.x + wdb.y * zb.y + wdb.z * zb.z + wdb.w * zb.w);
    acc += __shfl_xor(acc, 1);
    acc += __shfl_xor(acc, 2);
    acc += __shfl_xor(acc, 4);
    if (s8 == 0) out[(n << 6) + o8] = acc;
  }
}

extern "C" void kernel_launch(void* const* d_in, const int* in_sizes, int n_in,
                              void* d_out, int out_size, void* d_ws, size_t ws_size,
                              hipStream_t stream) {
  (void)in_sizes; (void)n_in; (void)out_size; (void)ws_size;
  const float* x  = (const float*)d_in[1];
  const float* v  = (const float*)d_in[2];
  const float* W1 = (const float*)d_in[3];
  const float* b1 = (const float*)d_in[4];
  const float* W2 = (const float*)d_in[5];
  const float* b2 = (const float*)d_in[6];
  const float* W3 = (const float*)d_in[7];
  unsigned short* W2sB = (unsigned short*)d_ws;       // 64*64*64 bf16 = 512 KB
  float* W1T = (float*)((char*)d_ws + (512 << 10));   // 16 KB
  float* b2s = W1T + 4096;                            // 16 KB

  hipLaunchKernelGGL(prep_kernel, dim3(130), dim3(256), 0, stream,
                     W2, W1, b2, W2sB, W1T, b2s);
  hipLaunchKernelGGL(conn_kernel, dim3(256), dim3(512), 0, stream,
                     x, v, W1, b1, W3, W2sB, W1T, b2s, (float*)d_out);
}

// Round 15
// 91.609 us; speedup vs baseline: 2.2812x; 1.0022x over previous
//
#include <hip/hip_runtime.h>
#include <math.h>
#include <stdint.h>

// n=256 samples, d=64, fp32 in/out. J-path bf16 MFMA.
//   K[m][l] = (1-h^2)[m] W1[m][l];  sKT[l][m] = K[m][l] (bf16), row 64 = h
//   W2sB[i][j][m] = bf16(W2[(i,j)][m] + W2[(j,i)][m])  (symmetric in i,j)
//   slab-frag af[t] and sKT-frag bf[t] are BOTH valid as A or B:
//     C1 = mfma(A=af[tr], B=bf[tc]) -> Ji[j][l];  C2 = mfma(A=bf[tr], B=af[tc])
//     -> Ji[l][j] at the SAME (lane,reg) => q in-register, no LDS transpose.
// Ledger: v7 512thr/128-VGPR spill-free (2 w/SIMD); v9 MFMA batching -2.9;
//   v10 pk-consume + 1-wave Jacobi -2.9; v11 W1T/b2s + 8x8 chains -2.3;
//   v12 net-zero; v13 DMA restored -0.5; v14 prologue/tail overlap -0.8.
//   Effective clock ~810MHz; the 268MB fill flushes L2 every iter => conn
//   starts cold. Serial-phase latency remains the lever.
// v15: (a) slab-0 DMA issued at KERNEL ENTRY (no deps; overlaps the whole
//   x/v->h->sKT prologue instead of adding ~900cy cold-HBM latency after
//   barrier 3); (b) ext (h-row) frags pinned in regs (+4 VGPR, ~118->~124
//   of 128 cap; removes ~60 ds_read_b128/wave from the i-loop);
//   (c) Jacobi 10->8 iters (rho~0.27 => residual ~3e-5 << 1e-3 floor;
//   absmax is the tripwire); (d) b1 early-issued with invariant loads.

typedef short short8 __attribute__((ext_vector_type(8)));
typedef float f32x4 __attribute__((ext_vector_type(4)));
typedef float f32x2 __attribute__((ext_vector_type(2)));

__device__ __forceinline__ unsigned short f2bf(float f) {
  unsigned int u = __builtin_bit_cast(unsigned int, f);
  u += 0x7fffu + ((u >> 16) & 1u);
  return (unsigned short)(u >> 16);
}

__device__ __forceinline__ short8 as_short8(uint4 u) {
  union { uint4 a; short8 b; } cv; cv.a = u; return cv.b;
}

// DMA one 8KB slab (64 rows x 128B) global->LDS, 16B/lane/instr, 8 instrs.
// Source pre-swizzled so lds[row j][16B-slot s] = global(j, s ^ (j&7)).
__device__ __forceinline__ void stage_slab(const unsigned short* gslab,
                                           unsigned short* lbase, int lane) {
  const int srcoff = ((lane >> 3) << 6) + (((lane & 7) ^ (lane >> 3)) << 3);  // shorts
  const unsigned short* gsrc = gslab + srcoff;
  #pragma unroll
  for (int k = 0; k < 8; ++k) {
    __builtin_amdgcn_global_load_lds(
        (const __attribute__((address_space(1))) unsigned int*)(gsrc + (k << 9)),
        (__attribute__((address_space(3))) unsigned int*)(lbase + (k << 9)),
        16, 0, 0);
  }
}

// Blocks 0-127: W2sB (bf16 symmetrized W2 slabs). Block 128: W1T (f32).
// Block 129: b2s = b2 + b2^T (f32). All sample-invariant.
__global__ __launch_bounds__(256) void prep_kernel(
    const float* __restrict__ W2, const float* __restrict__ W1,
    const float* __restrict__ b2, unsigned short* __restrict__ W2sB,
    float* __restrict__ W1T, float* __restrict__ b2s) {
  const int b = blockIdx.x;
  if (b < 128) {
    int g = b * 256 + threadIdx.x;      // each thread: 8 consecutive m
    int i = g >> 9, j = (g >> 3) & 63, m8 = (g & 7) << 3;
    const float* pa = &W2[((((i << 6) + j) << 6) + m8)];
    const float* pb = &W2[((((j << 6) + i) << 6) + m8)];
    float4 a0 = *(const float4*)pa, a1 = *(const float4*)(pa + 4);
    float4 b0 = *(const float4*)pb, b1 = *(const float4*)(pb + 4);
    short8 r;
    r[0] = (short)f2bf(a0.x + b0.x); r[1] = (short)f2bf(a0.y + b0.y);
    r[2] = (short)f2bf(a0.z + b0.z); r[3] = (short)f2bf(a0.w + b0.w);
    r[4] = (short)f2bf(a1.x + b1.x); r[5] = (short)f2bf(a1.y + b1.y);
    r[6] = (short)f2bf(a1.z + b1.z); r[7] = (short)f2bf(a1.w + b1.w);
    *(short8*)&W2sB[(size_t)g << 3] = r;
  } else if (b == 128) {
    for (int e = threadIdx.x; e < 4096; e += 256) {
      int l = e >> 6, m = e & 63;
      W1T[e] = W1[(m << 6) + l];              // W1T[l][m] = W1[m][l]
    }
  } else {
    for (int e = threadIdx.x; e < 4096; e += 256) {
      int r = e >> 6, c = e & 63;
      b2s[e] = b2[(r << 6) + c] + b2[(c << 6) + r];
    }
  }
}

__global__ __launch_bounds__(512) void conn_kernel(
    const float* __restrict__ x, const float* __restrict__ v,
    const float* __restrict__ W1, const float* __restrict__ b1,
    const float* __restrict__ W3, const unsigned short* __restrict__ W2sB,
    const float* __restrict__ W1T, const float* __restrict__ b2s,
    float* __restrict__ out) {
  __shared__ __align__(16) unsigned short sAF[8][2][4096];  // per-wave slab dbuf, 128KB
  __shared__ __align__(16) unsigned short sKT[80 * 80];  // rows 0-63 = K^T, 64 = h, 65-79 = 0
  __shared__ __align__(16) float sg[64 * 68];            // g, stride 68 (f32x4-aligned stores)
  __shared__ __align__(16) float sh[64], sv[64], sx[64];

  // Overlays into sKT rows 0-63 (bytes 0..10239): dead once bf frags are
  // pinned; ext reads use only rows 64-79 (bytes >= 10240).
  float* const spq = (float*)sKT;          // [8][64] = 2048B
  float* const szz = (float*)sKT + 576;    // [64] = 256B (z vector)

  const int n = blockIdx.x, t = threadIdx.x;
  const int wv = t >> 6, lane = t & 63, ln15 = lane & 15, quad = lane >> 4;
  const int o8 = t >> 3, s8 = t & 7;

  // ---- Issue slab-0 DMA FIRST: zero dependencies; its cold-HBM latency
  // (~900cy, L2 flushed by the harness fill) overlaps the whole prologue.
  unsigned short* const myAF = &sAF[wv][0][0];
  const unsigned short* const gbase = W2sB + ((size_t)(8 * wv) << 12);
  stage_slab(gbase, myAF, lane);   // slab 0 -> buf 0

  // ---- Early-issue all sample-invariant loads (complete by barrier 1's
  // vmcnt drain; latency overlaps the x/v hop). Regs die before i-loop.
  const float* w1r = &W1[(o8 << 6) + (s8 << 3)];
  float4 wa = *(const float4*)w1r, wb = *(const float4*)(w1r + 4);
  const int lL = t >> 3, m0 = (t & 7) << 3;          // sKT build: row lL, cols m0..m0+7
  float4 wt0 = *(const float4*)&W1T[(lL << 6) + m0];
  float4 wt1 = *(const float4*)&W1T[(lL << 6) + m0 + 4];
  const float b1v = b1[o8];

  if (t < 64) sx[t] = x[(n << 6) + t];
  else if (t < 128) sv[t - 64] = v[(n << 6) + (t - 64)];
  for (int e = t; e < 1280; e += 512) sKT[5120 + e] = 0;  // zero rows 64..79
  __syncthreads();

  // h[o] = tanh(b1[o] + sum_l sx[l] W1[o][l]); 8 lanes per output, shfl reduce
  {
    float4 xa = *(const float4*)&sx[s8 << 3], xb = *(const float4*)&sx[(s8 << 3) + 4];
    float acc = wa.x * xa.x + wa.y * xa.y + wa.z * xa.z + wa.w * xa.w
              + wb.x * xb.x + wb.y * xb.y + wb.z * xb.z + wb.w * xb.w;
    acc += __shfl_xor(acc, 1);
    acc += __shfl_xor(acc, 2);
    acc += __shfl_xor(acc, 4);
    if (s8 == 0) {
      float a = acc + b1v;
      a = fminf(10.f, fmaxf(-10.f, a));          // tanh(10)=1-4e-9, safe clamp
      float e2 = exp2f(a * 2.8853900817779268f); // e^(2a) via hw v_exp_f32
      sh[o8] = (e2 - 1.f) / (e2 + 1.f);
    }
  }
  __syncthreads();

  // sKT build: thread -> row lL, cols m0..m0+7; W1T chunk preloaded.
  {
    float4 h0 = *(const float4*)&sh[m0], h1 = *(const float4*)&sh[m0 + 4];
    short8 kk;
    kk[0] = (short)f2bf((1.f - h0.x * h0.x) * wt0.x);
    kk[1] = (short)f2bf((1.f - h0.y * h0.y) * wt0.y);
    kk[2] = (short)f2bf((1.f - h0.z * h0.z) * wt0.z);
    kk[3] = (short)f2bf((1.f - h0.w * h0.w) * wt0.w);
    kk[4] = (short)f2bf((1.f - h1.x * h1.x) * wt1.x);
    kk[5] = (short)f2bf((1.f - h1.y * h1.y) * wt1.y);
    kk[6] = (short)f2bf((1.f - h1.z * h1.z) * wt1.z);
    kk[7] = (short)f2bf((1.f - h1.w * h1.w) * wt1.w);
    *(short8*)&sKT[lL * 80 + m0] = kk;
  }
  if (t < 64) sKT[64 * 80 + t] = f2bf(sh[t]);
  __syncthreads();

  // sKT frags: tiles 0..3 dual-use (A for C2 row-tile / B for C1 col-tile).
  // Tile 4 (ext: h row) pinned in regs (v15: +4 VGPR, -60 ds_reads/wave).
  short8 bf[4][2];
  #pragma unroll
  for (int tc = 0; tc < 4; ++tc)
    #pragma unroll
    for (int ks = 0; ks < 2; ++ks)
      bf[tc][ks] = *(const short8*)&sKT[(tc * 16 + ln15) * 80 + ks * 32 + quad * 8];
  const int extoff = (64 + ln15) * 80 + quad * 8;
  const short8 e0 = *(const short8*)&sKT[extoff];
  const short8 e1 = *(const short8*)&sKT[extoff + 32];

  f32x2 qacc2[4] = {{0.f, 0.f}, {0.f, 0.f}, {0.f, 0.f}, {0.f, 0.f}};

  // Wave wv owns i in [8*wv, 8*wv+8). Slab frags from LDS, swizzled reads:
  // element slot' = slot ^ (ln15&7); af[tc][1] address = [0] address ^ 32.
  const int f0 = (ln15 << 6) + (((quad ^ ln15) & 7) << 3);

  #pragma unroll 1
  for (int ii = 0; ii < 8; ++ii) {
    asm volatile("s_waitcnt vmcnt(0)" ::: "memory");   // buf[ii&1] DMA complete
    __builtin_amdgcn_sched_barrier(0);
    if (ii < 7)  // prefetch next slab into the other buffer; flies across compute
      stage_slab(gbase + ((size_t)(ii + 1) << 12), myAF + (((ii & 1) ^ 1) << 12), lane);

    const unsigned short* buf = myAF + ((ii & 1) << 12);
    uint4 af[4][2];
    #pragma unroll
    for (int tc = 0; tc < 4; ++tc) {
      af[tc][0] = *(const uint4*)&buf[(tc << 10) + f0];
      af[tc][1] = *(const uint4*)&buf[(tc << 10) + (f0 ^ 32)];
    }
    const int i = 8 * wv + ii;
    const float vi = sv[i];

    #pragma unroll
    for (int tr = 0; tr < 4; ++tr) {
      short8 a0 = as_short8(af[tr][0]), a1 = as_short8(af[tr][1]);
      // Batch all 8 independent 2-deep MFMA chains before any VALU consume:
      // cross-tc ILP hides MFMA latency.
      f32x4 c1[4], c2[4];
      #pragma unroll
      for (int tc = 0; tc < 4; ++tc) {
        f32x4 z4 = {0.f, 0.f, 0.f, 0.f};
        f32x4 u = __builtin_amdgcn_mfma_f32_16x16x32_bf16(a0, bf[tc][0], z4, 0, 0, 0);
        c1[tc]  = __builtin_amdgcn_mfma_f32_16x16x32_bf16(a1, bf[tc][1], u, 0, 0, 0);
        f32x4 w = __builtin_amdgcn_mfma_f32_16x16x32_bf16(bf[tr][0], as_short8(af[tc][0]), z4, 0, 0, 0);
        c2[tc]  = __builtin_amdgcn_mfma_f32_16x16x32_bf16(bf[tr][1], as_short8(af[tc][1]), w, 0, 0, 0);
      }
      {
        f32x4 z4 = {0.f, 0.f, 0.f, 0.f};
        f32x4 u  = __builtin_amdgcn_mfma_f32_16x16x32_bf16(a0, e0, z4, 0, 0, 0);
        f32x4 ce = __builtin_amdgcn_mfma_f32_16x16x32_bf16(a1, e1, u, 0, 0, 0);
        if (ln15 == 0)  // g[i][j], j = 16*tr + 4*quad + r
          *(f32x4*)&sg[i * 68 + tr * 16 + quad * 4] = ce;
      }
      // Packed-fp32 consume: per tc 6 pk ops, fma folded into qacc2.
      f32x4 svj = *(const f32x4*)&sv[tr * 16 + quad * 4];
      f32x2 vi2 = {vi, vi};
      f32x2 w01 = f32x2{svj[0], svj[1]} * vi2;
      f32x2 w23 = f32x2{svj[2], svj[3]} * vi2;
      #pragma unroll
      for (int tc = 0; tc < 4; ++tc) {
        f32x2 c101 = {c1[tc][0], c1[tc][1]}, c123 = {c1[tc][2], c1[tc][3]};
        f32x2 c201 = {c2[tc][0], c2[tc][1]}, c223 = {c2[tc][2], c2[tc][3]};
        f32x2 t01 = (c101 * c101) * c201;
        f32x2 t23 = (c123 * c123) * c223;
        qacc2[tc] = __builtin_elementwise_fma(t01, w01, qacc2[tc]);
        qacc2[tc] = __builtin_elementwise_fma(t23, w23, qacc2[tc]);
      }
    }
  }

  // reduce qacc over quads (rows j), publish per-wave partial q.
  // spq overlays sKT rows 0-63: dead for ALL waves during/after the i-loop
  // (only rows 64-79 are read as ext frags), so no barrier needed first.
  #pragma unroll
  for (int tc = 0; tc < 4; ++tc) {
    float s = qacc2[tc][0] + qacc2[tc][1];
    s += __shfl_xor(s, 16, 64);
    s += __shfl_xor(s, 32, 64);
    if (quad == 0) spq[(wv << 6) + tc * 16 + ln15] = s;
  }

  // Hoisted output operands: accv = v @ W3[o8][:64]; wda/wdb = W3[o8][64:]
  // held across Jacobi (i-loop regs dead). Overlaps W3 L2 latency.
  float accv;
  float4 wda, wdb;
  {
    const float* w3r = &W3[o8 << 7];
    float4 wva = *(const float4*)&w3r[s8 << 3];
    float4 wvb = *(const float4*)&w3r[(s8 << 3) + 4];
    wda = *(const float4*)&w3r[64 + (s8 << 3)];
    wdb = *(const float4*)&w3r[64 + (s8 << 3) + 4];
    float4 va = *(const float4*)&sv[s8 << 3], vb = *(const float4*)&sv[(s8 << 3) + 4];
    accv = wva.x * va.x + wva.y * va.y + wva.z * va.z + wva.w * va.w
         + wvb.x * vb.x + wvb.y * vb.y + wvb.z * vb.z + wvb.w * vb.w;
  }

  // Jacobi wave pre-loads its b2s row BEFORE the barrier: the 16 f32x4
  // global loads complete during barrier arrival + vmcnt drain.
  f32x4 gr[16];
  float b2diag = 0.f;
  if (t < 64) {
    const float* b2row = &b2s[t << 6];
    #pragma unroll
    for (int cc = 0; cc < 16; ++cc) gr[cc] = *(const f32x4*)&b2row[cc << 2];
    b2diag = b2row[t];
  }
  __syncthreads();  // first block-wide sync since setup; sg/spq now visible

  // Jacobi: z' = z + (q - g z)/diag, g = sg + b2s (b2s folded into gr).
  // Single-wave register-matvec: lane r holds g-row r; z in LDS broadcast.
  // 8 independent 8-deep fma chains; NO per-iter drain (in-wave DS is
  // in-order). 8 iters: rho(D^-1 E)~0.27 => residual ~3e-5 << bf16-J
  // quantization floor ~1e-3. absmax is the tripwire.
  if (t < 64) {
    const float* grow = &sg[t * 68];
    #pragma unroll
    for (int cc = 0; cc < 16; ++cc) {
      f32x4 s4 = *(const f32x4*)&grow[cc << 2];
      gr[cc] += s4;
    }
    float q = spq[t] + spq[64 + t] + spq[128 + t] + spq[192 + t]
            + spq[256 + t] + spq[320 + t] + spq[384 + t] + spq[448 + t];
    const float dinv = 1.f / (grow[t] + b2diag);
    float zr = q * dinv;
    szz[t] = zr;
    #pragma unroll 1
    for (int it = 0; it < 8; ++it) {
      float p[8];
      #pragma unroll
      for (int cc = 0; cc < 8; ++cc) {
        f32x4 za_ = *(const f32x4*)&szz[cc << 3];
        f32x4 zb_ = *(const f32x4*)&szz[(cc << 3) + 4];
        f32x4 ga = gr[cc << 1], gb = gr[(cc << 1) + 1];
        float s = ga[0] * za_[0];
        s = fmaf(ga[1], za_[1], s);
        s = fmaf(ga[2], za_[2], s);
        s = fmaf(ga[3], za_[3], s);
        s = fmaf(gb[0], zb_[0], s);
        s = fmaf(gb[1], zb_[1], s);
        s = fmaf(gb[2], zb_[2], s);
        s = fmaf(gb[3], zb_[3], s);
        p[cc] = s;
      }
      float r4 = ((p[0] + p[1]) + (p[2] + p[3])) + ((p[4] + p[5]) + (p[6] + p[7]));
      zr = zr + (q - r4) * dinv;
      szz[t] = zr;
      __builtin_amdgcn_sched_barrier(0);
    }
  }
  __syncthreads();

  // out[o] = accv + 0.5 * sum_c z[c] W3[o][64+c]; 8 lanes/row
  {
    float4 za = *(const float4*)&szz[s8 << 3], zb = *(const float4*)&szz[(s8 << 3) + 4];
    float acc = accv
              + 0.5f * (wda.x * za.x + wda.y * za.y + wda.z * za.z + wda.w * za.w
                      + wdb.x * zb.x + wdb.y * zb.y + wdb.z * zb.z + wdb.w * zb.w);
    acc += __shfl_xor(acc, 1);
    acc += __shfl_xor(acc, 2);
    acc += __shfl_xor(acc, 4);
    if (s8 == 0) out[(n << 6) + o8] = acc;
  }
}

extern "C" void kernel_launch(void* const* d_in, const int* in_sizes, int n_in,
                              void* d_out, int out_size, void* d_ws, size_t ws_size,
                              hipStream_t stream) {
  (void)in_sizes; (void)n_in; (void)out_size; (void)ws_size;
  const float* x  = (const float*)d_in[1];
  const float* v  = (const float*)d_in[2];
  const float* W1 = (const float*)d_in[3];
  const float* b1 = (const float*)d_in[4];
  const float* W2 = (const float*)d_in[5];
  const float* b2 = (const float*)d_in[6];
  const float* W3 = (const float*)d_in[7];
  unsigned short* W2sB = (unsigned short*)d_ws;       // 64*64*64 bf16 = 512 KB
  float* W1T = (float*)((char*)d_ws + (512 << 10));   // 16 KB
  float* b2s = W1T + 4096;                            // 16 KB

  hipLaunchKernelGGL(prep_kernel, dim3(130), dim3(256), 0, stream,
                     W2, W1, b2, W2sB, W1T, b2s);
  hipLaunchKernelGGL(conn_kernel, dim3(256), dim3(512), 0, stream,
                     x, v, W1, b1, W3, W2sB, W1T, b2s, (float*)d_out);
}